// Round 1
// baseline (169.114 us; speedup 1.0000x reference)
//
#include <hip/hip_runtime.h>

#define B_   8
#define LQ_  128
#define LM_  512
#define D_   512
#define H_   256
#define MASKVAL -1e24f

__device__ __forceinline__ float tanh_fast(float x) {
    // tanh(x) = 1 - 2/(exp(2x)+1); exp via v_exp_f32 (2^x), rcp via v_rcp_f32
    float e = __builtin_amdgcn_exp2f(x * 2.88539008177792681f); // 2*log2(e)
    return fmaf(-2.0f, __builtin_amdgcn_rcpf(e + 1.0f), 1.0f);
}

// out[row][h] = dot(X[row][0:512], W[:,h]) + bias[h]; 16 rows per block, 256 threads (h)
__global__ __launch_bounds__(256) void proj_kernel(
    const float* __restrict__ X, const float* __restrict__ W,
    const float* __restrict__ bias, float* __restrict__ out)
{
    __shared__ float xs[16][512];           // 32 KB
    const int t = threadIdx.x;
    const int r0 = blockIdx.x * 16;
    for (int i = t; i < 16 * 512; i += 256) {
        int r = i >> 9, d = i & 511;
        xs[r][d] = X[(size_t)(r0 + r) * 512 + d];
    }
    __syncthreads();
    float acc[16];
    float b = bias ? bias[t] : 0.0f;
#pragma unroll
    for (int r = 0; r < 16; ++r) acc[r] = b;
#pragma unroll 4
    for (int d4 = 0; d4 < 128; ++d4) {
        float w0 = W[(4 * d4 + 0) * 256 + t];
        float w1 = W[(4 * d4 + 1) * 256 + t];
        float w2 = W[(4 * d4 + 2) * 256 + t];
        float w3 = W[(4 * d4 + 3) * 256 + t];
#pragma unroll
        for (int r = 0; r < 16; ++r) {
            float4 x4 = *(const float4*)&xs[r][4 * d4];  // uniform addr -> LDS broadcast
            acc[r] = fmaf(x4.w, w3, fmaf(x4.z, w2, fmaf(x4.y, w1, fmaf(x4.x, w0, acc[r]))));
        }
    }
#pragma unroll
    for (int r = 0; r < 16; ++r)
        out[(size_t)(r0 + r) * 256 + t] = acc[r];
}

// One block = (b, group of 4 q). 512 threads = 8 waves.
// wave w: q = w>>1, m-interleave half = w&1.
__global__ __launch_bounds__(512) void attn_kernel(
    const float* __restrict__ qp,      // [1024][256]
    const float* __restrict__ kp,      // [4096][256]
    const float* __restrict__ memory,  // [8][512][512]
    const int*   __restrict__ mask,    // [8][512]
    const float* __restrict__ v,       // [256]
    float* __restrict__ out_wm,        // [1024][512]
    float* __restrict__ out_w)         // [1024][512]
{
    __shared__ float scores[4][512];   // scores, then weights
    __shared__ int   mlist[512];
    __shared__ int   nact_sh;
    const int t = threadIdx.x;
    const int b  = blockIdx.x & 7;     // XCD swizzle: all blocks of batch b -> XCD b
    const int qg = blockIdx.x >> 3;    // 0..31
    const int rowbase = b * LQ_ + qg * 4;
    const int w = t >> 6, lane = t & 63;

    for (int i = t; i < 4 * 512; i += 512) (&scores[0][0])[i] = MASKVAL;

    // compact active (unmasked) m list — wave 0 only
    if (w == 0) {
        unsigned base = 0;
        for (int it = 0; it < 8; ++it) {
            int m = it * 64 + lane;
            int act = (mask[b * 512 + m] == 0);
            unsigned long long bal = __ballot(act);
            if (act) {
                int pos = __popcll(bal & ((1ull << lane) - 1ull));
                mlist[base + pos] = m;
            }
            base += __popcll(bal);
        }
        if (lane == 0) nact_sh = (int)base;
    }
    __syncthreads();
    const int nact = nact_sh;

    // ---- phase 1: scores[q][m] = sum_h v[h]*tanh(qp[q][h]+kp[m][h]) ----
    {
        const int q = w >> 1, half = w & 1;
        const int lane16 = lane & 15, mg = lane >> 4;  // 4 m per wave-iter, 16 lanes/m
        const int row = rowbase + q;
        float qreg[16], vreg[16];
        const float4* qrp = (const float4*)(qp + (size_t)row * 256 + lane16 * 16);
        const float4* vrp = (const float4*)(v + lane16 * 16);
#pragma unroll
        for (int j = 0; j < 4; ++j) {
            float4 a = qrp[j], c = vrp[j];
            qreg[4 * j + 0] = a.x; qreg[4 * j + 1] = a.y; qreg[4 * j + 2] = a.z; qreg[4 * j + 3] = a.w;
            vreg[4 * j + 0] = c.x; vreg[4 * j + 1] = c.y; vreg[4 * j + 2] = c.z; vreg[4 * j + 3] = c.w;
        }
        const int nit = (nact + 7) >> 3;
        for (int it = 0; it < nit; ++it) {
            int i = it * 8 + half * 4 + mg;
            if (i < nact) {
                int m = mlist[i];
                const float4* kr = (const float4*)(kp + (size_t)(b * 512 + m) * 256 + lane16 * 16);
                float p = 0.0f;
#pragma unroll
                for (int j = 0; j < 4; ++j) {
                    float4 k4 = kr[j];
                    p = fmaf(vreg[4 * j + 0], tanh_fast(qreg[4 * j + 0] + k4.x), p);
                    p = fmaf(vreg[4 * j + 1], tanh_fast(qreg[4 * j + 1] + k4.y), p);
                    p = fmaf(vreg[4 * j + 2], tanh_fast(qreg[4 * j + 2] + k4.z), p);
                    p = fmaf(vreg[4 * j + 3], tanh_fast(qreg[4 * j + 3] + k4.w), p);
                }
                p += __shfl_xor(p, 1);
                p += __shfl_xor(p, 2);
                p += __shfl_xor(p, 4);
                p += __shfl_xor(p, 8);
                if (lane16 == 0) scores[q][m] = p;
            }
        }
    }
    __syncthreads();

    // ---- phase 2: softmax per q (waves 0..3), weights -> scores + out_w ----
    if (w < 4) {
        const int q = w, row = rowbase + q;
        float s[8], e[8];
        float mx = -INFINITY;
#pragma unroll
        for (int k = 0; k < 8; ++k) { s[k] = scores[q][lane + 64 * k]; mx = fmaxf(mx, s[k]); }
#pragma unroll
        for (int off = 32; off >= 1; off >>= 1) mx = fmaxf(mx, __shfl_xor(mx, off));
        float sum = 0.0f;
#pragma unroll
        for (int k = 0; k < 8; ++k) {
            e[k] = __builtin_amdgcn_exp2f((s[k] - mx) * 1.44269504088896341f);
            sum += e[k];
        }
#pragma unroll
        for (int off = 32; off >= 1; off >>= 1) sum += __shfl_xor(sum, off);
        float rs = __builtin_amdgcn_rcpf(sum);
#pragma unroll
        for (int k = 0; k < 8; ++k) {
            float wt = e[k] * rs;
            scores[q][lane + 64 * k] = wt;
            out_w[(size_t)row * 512 + lane + 64 * k] = wt;
        }
    }
    __syncthreads();

    // ---- phase 3: weighted_memory[q][d] = sum_m w[q][m] * memory[b][m][d] ----
    {
        const int d = t;
        float a0 = 0, a1 = 0, a2 = 0, a3 = 0;
        int i = 0;
        for (; i + 2 <= nact; i += 2) {
            int m0 = mlist[i], m1 = mlist[i + 1];
            float v0 = memory[(size_t)(b * 512 + m0) * 512 + d];
            float v1 = memory[(size_t)(b * 512 + m1) * 512 + d];
            a0 = fmaf(scores[0][m1], v1, fmaf(scores[0][m0], v0, a0));
            a1 = fmaf(scores[1][m1], v1, fmaf(scores[1][m0], v0, a1));
            a2 = fmaf(scores[2][m1], v1, fmaf(scores[2][m0], v0, a2));
            a3 = fmaf(scores[3][m1], v1, fmaf(scores[3][m0], v0, a3));
        }
        for (; i < nact; ++i) {
            int m0 = mlist[i];
            float v0 = memory[(size_t)(b * 512 + m0) * 512 + d];
            a0 = fmaf(scores[0][m0], v0, a0);
            a1 = fmaf(scores[1][m0], v0, a1);
            a2 = fmaf(scores[2][m0], v0, a2);
            a3 = fmaf(scores[3][m0], v0, a3);
        }
        out_wm[(size_t)(rowbase + 0) * 512 + d] = a0;
        out_wm[(size_t)(rowbase + 1) * 512 + d] = a1;
        out_wm[(size_t)(rowbase + 2) * 512 + d] = a2;
        out_wm[(size_t)(rowbase + 3) * 512 + d] = a3;
    }
}

extern "C" void kernel_launch(void* const* d_in, const int* in_sizes, int n_in,
                              void* d_out, int out_size, void* d_ws, size_t ws_size,
                              hipStream_t stream) {
    const float* query  = (const float*)d_in[0];  // [8,128,512]
    const float* memory = (const float*)d_in[1];  // [8,512,512]
    const int*   mask   = (const int*)  d_in[2];  // [8,512] bool->int32
    const float* Wq     = (const float*)d_in[3];  // [512,256]
    const float* bq     = (const float*)d_in[4];  // [256]
    const float* Wm     = (const float*)d_in[5];  // [512,256]
    const float* v      = (const float*)d_in[6];  // [256]

    float* out_wm = (float*)d_out;                         // [1024][512]
    float* out_w  = out_wm + (size_t)B_ * LQ_ * D_;        // [1024][512]

    float* qp = (float*)d_ws;                              // [1024][256] = 1 MB
    float* kp = qp + (size_t)B_ * LQ_ * H_;                // [4096][256] = 4 MB

    hipLaunchKernelGGL(proj_kernel, dim3((B_ * LQ_) / 16), dim3(256), 0, stream,
                       query, Wq, bq, qp);
    hipLaunchKernelGGL(proj_kernel, dim3((B_ * LM_) / 16), dim3(256), 0, stream,
                       memory, Wm, nullptr, kp);
    hipLaunchKernelGGL(attn_kernel, dim3(B_ * (LQ_ / 4)), dim3(512), 0, stream,
                       qp, kp, memory, mask, v, out_wm, out_w);
}

// Round 2
// 83.014 us; speedup vs baseline: 2.0372x; 2.0372x over previous
//
#include <hip/hip_runtime.h>

#define B_   8
#define LQ_  128
#define LM_  512
#define D_   512
#define H_   256
#define MASKVAL -1e24f

__device__ __forceinline__ float tanh_fast(float x) {
    float e = __builtin_amdgcn_exp2f(x * 2.88539008177792681f); // 2*log2(e)
    return fmaf(-2.0f, __builtin_amdgcn_rcpf(e + 1.0f), 1.0f);
}

// ---------------- fused projection GEMM ----------------
// rows 0..1023:  query @ Wq + bq -> qp   [1024,256]
// rows 1024..5119: memory @ Wm -> kp     [4096,256]
#define BM 64
#define BN 64
#define BK 64

__global__ __launch_bounds__(256) void proj_kernel(
    const float* __restrict__ query, const float* __restrict__ memory,
    const float* __restrict__ Wq, const float* __restrict__ Wm,
    const float* __restrict__ bq,
    float* __restrict__ qp, float* __restrict__ kp)
{
    __shared__ float Xs[BM][BK + 4];   // [row][k], +4 pad: aligned b128, banks spread
    __shared__ float Ws[BK][BN];       // [k][n], unpadded: b128 r/w at bank minimum

    const int mtile = blockIdx.x >> 2;           // 0..79
    const int n0    = (blockIdx.x & 3) * BN;     // 0..192
    const bool is_q = (mtile < 16);
    const float* X = is_q ? (query  + (size_t)mtile * BM * D_)
                          : (memory + (size_t)(mtile - 16) * BM * D_);
    const float* W = is_q ? Wq : Wm;
    float* out     = is_q ? (qp + (size_t)mtile * BM * H_)
                          : (kp + (size_t)(mtile - 16) * BM * H_);

    const int t  = threadIdx.x;
    const int tx = t & 15;   // output cols 4*tx..4*tx+3
    const int ty = t >> 4;   // output rows 4*ty..4*ty+3
    const int sx = t & 15;   // staging float4 index
    const int sy = t >> 4;   // staging row base (16 rows/pass)

    float acc[4][4];
#pragma unroll
    for (int i = 0; i < 4; ++i)
#pragma unroll
        for (int j = 0; j < 4; ++j) acc[i][j] = 0.0f;

    for (int k0 = 0; k0 < D_; k0 += BK) {
        // stage X tile [64 rows][64 k]
#pragma unroll
        for (int p = 0; p < 4; ++p) {
            const int row = sy + p * 16;
            const float4 x4 = *(const float4*)(X + (size_t)row * D_ + k0 + sx * 4);
            *(float4*)&Xs[row][sx * 4] = x4;
        }
        // stage W tile [64 k][64 n]
#pragma unroll
        for (int p = 0; p < 4; ++p) {
            const int kk = sy + p * 16;
            const float4 w4 = *(const float4*)(W + (size_t)(k0 + kk) * H_ + n0 + sx * 4);
            *(float4*)&Ws[kk][sx * 4] = w4;
        }
        __syncthreads();

#pragma unroll 2
        for (int kk0 = 0; kk0 < BK; kk0 += 4) {
            float4 a[4], b[4];
#pragma unroll
            for (int i = 0; i < 4; ++i) a[i] = *(const float4*)&Xs[4 * ty + i][kk0];
#pragma unroll
            for (int kj = 0; kj < 4; ++kj) b[kj] = *(const float4*)&Ws[kk0 + kj][4 * tx];
#pragma unroll
            for (int i = 0; i < 4; ++i) {
                const float* ap = (const float*)&a[i];
#pragma unroll
                for (int kj = 0; kj < 4; ++kj) {
                    const float* bp = (const float*)&b[kj];
                    acc[i][0] = fmaf(ap[kj], bp[0], acc[i][0]);
                    acc[i][1] = fmaf(ap[kj], bp[1], acc[i][1]);
                    acc[i][2] = fmaf(ap[kj], bp[2], acc[i][2]);
                    acc[i][3] = fmaf(ap[kj], bp[3], acc[i][3]);
                }
            }
        }
        __syncthreads();
    }

    float4 bias4 = make_float4(0.f, 0.f, 0.f, 0.f);
    if (is_q) bias4 = *(const float4*)(bq + n0 + tx * 4);
#pragma unroll
    for (int i = 0; i < 4; ++i) {
        float4 o;
        o.x = acc[i][0] + bias4.x;
        o.y = acc[i][1] + bias4.y;
        o.z = acc[i][2] + bias4.z;
        o.w = acc[i][3] + bias4.w;
        *(float4*)(out + (size_t)(4 * ty + i) * H_ + n0 + tx * 4) = o;
    }
}

// ---------------- fused score/softmax/PV ----------------
// One block = (b, group of 4 q). 512 threads = 8 waves.
__global__ __launch_bounds__(512) void attn_kernel(
    const float* __restrict__ qp,      // [1024][256]
    const float* __restrict__ kp,      // [4096][256]
    const float* __restrict__ memory,  // [8][512][512]
    const int*   __restrict__ mask,    // [8][512]
    const float* __restrict__ v,       // [256]
    float* __restrict__ out_wm,        // [1024][512]
    float* __restrict__ out_w)         // [1024][512]
{
    __shared__ float scores[4][512];   // scores, then weights
    __shared__ int   mlist[512];
    __shared__ int   nact_sh;
    const int t = threadIdx.x;
    const int b  = blockIdx.x & 7;     // XCD swizzle: all blocks of batch b -> XCD b
    const int qg = blockIdx.x >> 3;    // 0..31
    const int rowbase = b * LQ_ + qg * 4;
    const int w = t >> 6, lane = t & 63;

    for (int i = t; i < 4 * 512; i += 512) (&scores[0][0])[i] = MASKVAL;

    // compact active (unmasked) m list — wave 0 only
    if (w == 0) {
        unsigned base = 0;
        for (int it = 0; it < 8; ++it) {
            int m = it * 64 + lane;
            int act = (mask[b * 512 + m] == 0);
            unsigned long long bal = __ballot(act);
            if (act) {
                int pos = __popcll(bal & ((1ull << lane) - 1ull));
                mlist[base + pos] = m;
            }
            base += __popcll(bal);
        }
        if (lane == 0) nact_sh = (int)base;
    }
    __syncthreads();
    const int nact = nact_sh;

    // ---- phase 1: scores[q][m] = sum_h v[h]*tanh(qp[q][h]+kp[m][h]) ----
    {
        const int q = w >> 1, half = w & 1;
        const int lane16 = lane & 15, mg = lane >> 4;  // 4 m per wave-iter, 16 lanes/m
        const int row = rowbase + q;
        float qreg[16], vreg[16];
        const float4* qrp = (const float4*)(qp + (size_t)row * 256 + lane16 * 16);
        const float4* vrp = (const float4*)(v + lane16 * 16);
#pragma unroll
        for (int j = 0; j < 4; ++j) {
            float4 a = qrp[j], c = vrp[j];
            qreg[4 * j + 0] = a.x; qreg[4 * j + 1] = a.y; qreg[4 * j + 2] = a.z; qreg[4 * j + 3] = a.w;
            vreg[4 * j + 0] = c.x; vreg[4 * j + 1] = c.y; vreg[4 * j + 2] = c.z; vreg[4 * j + 3] = c.w;
        }
        const int nit = (nact + 7) >> 3;
        for (int it = 0; it < nit; ++it) {
            int i = it * 8 + half * 4 + mg;
            if (i < nact) {
                int m = mlist[i];
                const float4* kr = (const float4*)(kp + (size_t)(b * 512 + m) * 256 + lane16 * 16);
                float p = 0.0f;
#pragma unroll
                for (int j = 0; j < 4; ++j) {
                    float4 k4 = kr[j];
                    p = fmaf(vreg[4 * j + 0], tanh_fast(qreg[4 * j + 0] + k4.x), p);
                    p = fmaf(vreg[4 * j + 1], tanh_fast(qreg[4 * j + 1] + k4.y), p);
                    p = fmaf(vreg[4 * j + 2], tanh_fast(qreg[4 * j + 2] + k4.z), p);
                    p = fmaf(vreg[4 * j + 3], tanh_fast(qreg[4 * j + 3] + k4.w), p);
                }
                p += __shfl_xor(p, 1);
                p += __shfl_xor(p, 2);
                p += __shfl_xor(p, 4);
                p += __shfl_xor(p, 8);
                if (lane16 == 0) scores[q][m] = p;
            }
        }
    }
    __syncthreads();

    // ---- phase 2: softmax per q (waves 0..3) ----
    if (w < 4) {
        const int q = w, row = rowbase + q;
        float s[8], e[8];
        float mx = -INFINITY;
#pragma unroll
        for (int k = 0; k < 8; ++k) { s[k] = scores[q][lane + 64 * k]; mx = fmaxf(mx, s[k]); }
#pragma unroll
        for (int off = 32; off >= 1; off >>= 1) mx = fmaxf(mx, __shfl_xor(mx, off));
        float sum = 0.0f;
#pragma unroll
        for (int k = 0; k < 8; ++k) {
            e[k] = __builtin_amdgcn_exp2f((s[k] - mx) * 1.44269504088896341f);
            sum += e[k];
        }
#pragma unroll
        for (int off = 32; off >= 1; off >>= 1) sum += __shfl_xor(sum, off);
        float rs = __builtin_amdgcn_rcpf(sum);
#pragma unroll
        for (int k = 0; k < 8; ++k) {
            float wt = e[k] * rs;
            scores[q][lane + 64 * k] = wt;
            out_w[(size_t)row * 512 + lane + 64 * k] = wt;
        }
    }
    __syncthreads();

    // ---- phase 3: weighted_memory[q][d] = sum_m w[q][m] * memory[b][m][d] ----
    {
        const int d = t;
        float a0 = 0, a1 = 0, a2 = 0, a3 = 0;
        int i = 0;
        for (; i + 2 <= nact; i += 2) {
            int m0 = mlist[i], m1 = mlist[i + 1];
            float v0 = memory[(size_t)(b * 512 + m0) * 512 + d];
            float v1 = memory[(size_t)(b * 512 + m1) * 512 + d];
            a0 = fmaf(scores[0][m1], v1, fmaf(scores[0][m0], v0, a0));
            a1 = fmaf(scores[1][m1], v1, fmaf(scores[1][m0], v0, a1));
            a2 = fmaf(scores[2][m1], v1, fmaf(scores[2][m0], v0, a2));
            a3 = fmaf(scores[3][m1], v1, fmaf(scores[3][m0], v0, a3));
        }
        for (; i < nact; ++i) {
            int m0 = mlist[i];
            float v0 = memory[(size_t)(b * 512 + m0) * 512 + d];
            a0 = fmaf(scores[0][m0], v0, a0);
            a1 = fmaf(scores[1][m0], v0, a1);
            a2 = fmaf(scores[2][m0], v0, a2);
            a3 = fmaf(scores[3][m0], v0, a3);
        }
        out_wm[(size_t)(rowbase + 0) * 512 + d] = a0;
        out_wm[(size_t)(rowbase + 1) * 512 + d] = a1;
        out_wm[(size_t)(rowbase + 2) * 512 + d] = a2;
        out_wm[(size_t)(rowbase + 3) * 512 + d] = a3;
    }
}

extern "C" void kernel_launch(void* const* d_in, const int* in_sizes, int n_in,
                              void* d_out, int out_size, void* d_ws, size_t ws_size,
                              hipStream_t stream) {
    const float* query  = (const float*)d_in[0];  // [8,128,512]
    const float* memory = (const float*)d_in[1];  // [8,512,512]
    const int*   mask   = (const int*)  d_in[2];  // [8,512]
    const float* Wq     = (const float*)d_in[3];  // [512,256]
    const float* bq     = (const float*)d_in[4];  // [256]
    const float* Wm     = (const float*)d_in[5];  // [512,256]
    const float* v      = (const float*)d_in[6];  // [256]

    float* out_wm = (float*)d_out;                         // [1024][512]
    float* out_w  = out_wm + (size_t)B_ * LQ_ * D_;        // [1024][512]

    float* qp = (float*)d_ws;                              // [1024][256] = 1 MB
    float* kp = qp + (size_t)B_ * LQ_ * H_;                // [4096][256] = 4 MB

    hipLaunchKernelGGL(proj_kernel, dim3((B_ * (LQ_ + LM_)) / BM * (H_ / BN)), dim3(256), 0, stream,
                       query, memory, Wq, Wm, bq, qp, kp);
    hipLaunchKernelGGL(attn_kernel, dim3(B_ * (LQ_ / 4)), dim3(512), 0, stream,
                       qp, kp, memory, mask, v, out_wm, out_w);
}

// Round 3
// 66.459 us; speedup vs baseline: 2.5446x; 1.2491x over previous
//
#include <hip/hip_runtime.h>
#include <hip/hip_bf16.h>

#define B_   8
#define LQ_  128
#define LM_  512
#define D_   512
#define H_   256
#define MASKVAL -1e24f
#define PRESCALE 2.88539008177792681f  // 2*log2(e): exp2(PRESCALE*x) = e^(2x)

typedef __attribute__((ext_vector_type(8))) short bf16x8;
typedef __attribute__((ext_vector_type(4))) float f32x4;

__device__ __forceinline__ ushort f2bf(float x) {
    return __builtin_bit_cast(ushort, __float2bfloat16(x));
}

// ---------------- MFMA projection GEMM (bf16 inputs, f32 accum) ----------------
// rows 0..1023:  query @ Wq + bq -> qp   [1024,256]   (output prescaled)
// rows 1024..5119: memory @ Wm -> kp     [4096,256]   (output prescaled)
#define PBM 32
#define PBN 32
#define PBK 64
#define PLDK 88   // padded k-stride (ushorts) = 176 B: 16B-aligned, 2-way banks

__global__ __launch_bounds__(256) void proj_mfma(
    const float* __restrict__ query, const float* __restrict__ memory,
    const float* __restrict__ Wq, const float* __restrict__ Wm,
    const float* __restrict__ bq,
    float* __restrict__ qp, float* __restrict__ kp)
{
    __shared__ ushort As[PBM][PLDK];
    __shared__ ushort Bs[PBN][PLDK];   // stores W^T tile: Bs[n][k]

    const int mtile = blockIdx.x % 160;   // same-mtile blocks land on same XCD
    const int ntile = blockIdx.x / 160;   // 0..7
    const int n0 = ntile * PBN;
    const bool is_q = (mtile < 32);
    const float* X = is_q ? (query  + (size_t)mtile * PBM * D_)
                          : (memory + (size_t)(mtile - 32) * PBM * D_);
    const float* W = is_q ? Wq : Wm;
    float* out     = is_q ? (qp + (size_t)mtile * PBM * H_)
                          : (kp + (size_t)(mtile - 32) * PBM * H_);

    const int t = threadIdx.x;
    const int lane = t & 63, w = t >> 6;
    const int wm = (w & 1) * 16, wn = (w >> 1) * 16;  // wave tile 16x16

    // staging indices
    const int ar  = t >> 4;   // A row (2 passes of 16)
    const int akq = t & 15;   // A k-quad
    const int bn  = t >> 3;   // B n-row 0..31
    const int bk2 = t & 7;    // B k-pair slot

    // fragment addressing (assumed std layout; K-permutation cancels A vs B)
    const int frow = lane & 15;
    const int fkof = (lane >> 4) * 8;

    f32x4 acc = {0.f, 0.f, 0.f, 0.f};

    for (int k0 = 0; k0 < D_; k0 += PBK) {
        // stage A: X[32][64] f32 -> bf16
#pragma unroll
        for (int p = 0; p < 2; ++p) {
            const int row = ar + p * 16;
            const float4 x4 = *(const float4*)(X + (size_t)row * D_ + k0 + akq * 4);
            ushort4 u4;
            u4.x = f2bf(x4.x); u4.y = f2bf(x4.y); u4.z = f2bf(x4.z); u4.w = f2bf(x4.w);
            *(ushort4*)&As[row][akq * 4] = u4;
        }
        // stage B transposed: W[k][n] -> Bs[n][k] bf16
#pragma unroll
        for (int kp4 = 0; kp4 < 4; ++kp4) {
            const int kk = kp4 * 16 + bk2 * 2;
            const float* wp = W + (size_t)(k0 + kk) * H_ + n0 + bn;
            const float w0 = wp[0], w1 = wp[H_];
            ushort2 u2; u2.x = f2bf(w0); u2.y = f2bf(w1);
            *(ushort2*)&Bs[bn][kk] = u2;
        }
        __syncthreads();
#pragma unroll
        for (int ks = 0; ks < PBK; ks += 32) {
            bf16x8 a = *(const bf16x8*)&As[wm + frow][ks + fkof];
            bf16x8 b = *(const bf16x8*)&Bs[wn + frow][ks + fkof];
            acc = __builtin_amdgcn_mfma_f32_16x16x32_bf16(a, b, acc, 0, 0, 0);
        }
        __syncthreads();
    }

    // epilogue: C/D layout (verified): col = lane&15, row = (lane>>4)*4 + r
    const int col  = n0 + wn + (lane & 15);
    const int rloc = wm + (lane >> 4) * 4;
    const float bias = is_q ? bq[col] : 0.0f;
#pragma unroll
    for (int r = 0; r < 4; ++r)
        out[(size_t)(rloc + r) * H_ + col] = (acc[r] + bias) * PRESCALE;
}

// ---------------- fused score/softmax/PV ----------------
// One block = (b, pair of q). 512 threads = 8 waves; 512 blocks (2/CU).
__global__ __launch_bounds__(512) void attn_kernel(
    const float* __restrict__ qp,      // [1024][256] prescaled
    const float* __restrict__ kp,      // [4096][256] prescaled
    const float* __restrict__ memory,  // [8][512][512]
    const int*   __restrict__ mask,    // [8][512]
    const float* __restrict__ v,       // [256]
    float* __restrict__ out_wm,        // [1024][512]
    float* __restrict__ out_w)         // [1024][512]
{
    __shared__ float scores[2][512];
    __shared__ int   mlist[512];
    __shared__ int   nact_sh;
    const int t = threadIdx.x;
    const int b  = blockIdx.x & 7;     // all blocks of batch b -> XCD b
    const int qg = blockIdx.x >> 3;    // 0..63
    const int rowbase = b * LQ_ + qg * 2;
    const int w = t >> 6, lane = t & 63;

    for (int i = t; i < 2 * 512; i += 512) (&scores[0][0])[i] = MASKVAL;

    if (w == 0) {
        unsigned base = 0;
        for (int it = 0; it < 8; ++it) {
            int m = it * 64 + lane;
            int act = (mask[b * 512 + m] == 0);
            unsigned long long bal = __ballot(act);
            if (act) {
                int pos = __popcll(bal & ((1ull << lane) - 1ull));
                mlist[base + pos] = m;
            }
            base += __popcll(bal);
        }
        if (lane == 0) nact_sh = (int)base;
    }
    __syncthreads();
    const int nact = nact_sh;

    // ---- phase 1: scores[q][m] = vsum - 2 * sum_h v[h]/(e^{2(qp+kp)}+1) ----
    {
        const int q = w >> 2, quarter = w & 3;
        const int lane16 = lane & 15, mg = lane >> 4;
        const int row = rowbase + q;
        float qreg[16], vreg[16];
        const float4* qrp = (const float4*)(qp + (size_t)row * 256 + lane16 * 16);
        const float4* vrp = (const float4*)(v + lane16 * 16);
        float sv = 0.0f;
#pragma unroll
        for (int j = 0; j < 4; ++j) {
            float4 a = qrp[j], c = vrp[j];
            qreg[4 * j + 0] = a.x; qreg[4 * j + 1] = a.y; qreg[4 * j + 2] = a.z; qreg[4 * j + 3] = a.w;
            vreg[4 * j + 0] = c.x; vreg[4 * j + 1] = c.y; vreg[4 * j + 2] = c.z; vreg[4 * j + 3] = c.w;
            sv += c.x + c.y + c.z + c.w;
        }
        sv += __shfl_xor(sv, 1); sv += __shfl_xor(sv, 2);
        sv += __shfl_xor(sv, 4); sv += __shfl_xor(sv, 8);

        const int nit = (nact + 15) >> 4;
        for (int it = 0; it < nit; ++it) {
            int i = it * 16 + quarter * 4 + mg;
            if (i < nact) {
                int m = mlist[i];
                const float4* kr = (const float4*)(kp + (size_t)(b * 512 + m) * 256 + lane16 * 16);
                float p0 = 0.0f, p1 = 0.0f;
#pragma unroll
                for (int j = 0; j < 4; ++j) {
                    float4 k4 = kr[j];
                    p0 = fmaf(vreg[4 * j + 0], __builtin_amdgcn_rcpf(__builtin_amdgcn_exp2f(qreg[4 * j + 0] + k4.x) + 1.0f), p0);
                    p1 = fmaf(vreg[4 * j + 1], __builtin_amdgcn_rcpf(__builtin_amdgcn_exp2f(qreg[4 * j + 1] + k4.y) + 1.0f), p1);
                    p0 = fmaf(vreg[4 * j + 2], __builtin_amdgcn_rcpf(__builtin_amdgcn_exp2f(qreg[4 * j + 2] + k4.z) + 1.0f), p0);
                    p1 = fmaf(vreg[4 * j + 3], __builtin_amdgcn_rcpf(__builtin_amdgcn_exp2f(qreg[4 * j + 3] + k4.w) + 1.0f), p1);
                }
                float pr = p0 + p1;
                pr += __shfl_xor(pr, 1); pr += __shfl_xor(pr, 2);
                pr += __shfl_xor(pr, 4); pr += __shfl_xor(pr, 8);
                if (lane16 == 0) scores[q][m] = sv - 2.0f * pr;
            }
        }
    }
    __syncthreads();

    // ---- phase 2: softmax per q (waves 0..1) ----
    if (w < 2) {
        const int q = w, row = rowbase + q;
        float s[8], e[8];
        float mx = -INFINITY;
#pragma unroll
        for (int k = 0; k < 8; ++k) { s[k] = scores[q][lane + 64 * k]; mx = fmaxf(mx, s[k]); }
#pragma unroll
        for (int off = 32; off >= 1; off >>= 1) mx = fmaxf(mx, __shfl_xor(mx, off));
        float sum = 0.0f;
#pragma unroll
        for (int k = 0; k < 8; ++k) {
            e[k] = __builtin_amdgcn_exp2f((s[k] - mx) * 1.44269504088896341f);
            sum += e[k];
        }
#pragma unroll
        for (int off = 32; off >= 1; off >>= 1) sum += __shfl_xor(sum, off);
        float rs = __builtin_amdgcn_rcpf(sum);
#pragma unroll
        for (int k = 0; k < 8; ++k) {
            float wt = e[k] * rs;
            scores[q][lane + 64 * k] = wt;
            out_w[(size_t)row * 512 + lane + 64 * k] = wt;
        }
    }
    __syncthreads();

    // ---- phase 3: weighted_memory ----
    {
        const int d = t;
        float a0 = 0.f, a1 = 0.f;
        int i = 0;
        for (; i + 2 <= nact; i += 2) {
            int m0 = mlist[i], m1 = mlist[i + 1];
            float v0 = memory[(size_t)(b * 512 + m0) * 512 + d];
            float v1 = memory[(size_t)(b * 512 + m1) * 512 + d];
            a0 = fmaf(scores[0][m1], v1, fmaf(scores[0][m0], v0, a0));
            a1 = fmaf(scores[1][m1], v1, fmaf(scores[1][m0], v0, a1));
        }
        if (i < nact) {
            int m0 = mlist[i];
            float v0 = memory[(size_t)(b * 512 + m0) * 512 + d];
            a0 = fmaf(scores[0][m0], v0, a0);
            a1 = fmaf(scores[1][m0], v0, a1);
        }
        out_wm[(size_t)(rowbase + 0) * 512 + d] = a0;
        out_wm[(size_t)(rowbase + 1) * 512 + d] = a1;
    }
}

extern "C" void kernel_launch(void* const* d_in, const int* in_sizes, int n_in,
                              void* d_out, int out_size, void* d_ws, size_t ws_size,
                              hipStream_t stream) {
    const float* query  = (const float*)d_in[0];  // [8,128,512]
    const float* memory = (const float*)d_in[1];  // [8,512,512]
    const int*   mask   = (const int*)  d_in[2];  // [8,512]
    const float* Wq     = (const float*)d_in[3];  // [512,256]
    const float* bq     = (const float*)d_in[4];  // [256]
    const float* Wm     = (const float*)d_in[5];  // [512,256]
    const float* v      = (const float*)d_in[6];  // [256]

    float* out_wm = (float*)d_out;                         // [1024][512]
    float* out_w  = out_wm + (size_t)B_ * LQ_ * D_;        // [1024][512]

    float* qp = (float*)d_ws;                              // [1024][256] = 1 MB
    float* kp = qp + (size_t)B_ * LQ_ * H_;                // [4096][256] = 4 MB

    hipLaunchKernelGGL(proj_mfma, dim3(160 * (H_ / PBN)), dim3(256), 0, stream,
                       query, memory, Wq, Wm, bq, qp, kp);
    hipLaunchKernelGGL(attn_kernel, dim3(B_ * (LQ_ / 2)), dim3(512), 0, stream,
                       qp, kp, memory, mask, v, out_wm, out_w);
}

// Round 4
// 66.435 us; speedup vs baseline: 2.5455x; 1.0004x over previous
//
#include <hip/hip_runtime.h>
#include <hip/hip_bf16.h>

#define B_   8
#define LQ_  128
#define LM_  512
#define D_   512
#define H_   256
#define MASKVAL -1e24f
#define PRESCALE 2.88539008177792681f  // 2*log2(e): exp2(PRESCALE*x) = e^(2x)

typedef __attribute__((ext_vector_type(8))) short bf16x8;
typedef __attribute__((ext_vector_type(4))) float f32x4;

__device__ __forceinline__ ushort f2bf(float x) {
    return __builtin_bit_cast(ushort, __float2bfloat16(x));
}

// ---------------- MFMA projection GEMM (bf16 inputs, f32 accum) ----------------
#define PBM 32
#define PBN 32
#define PBK 64
#define PLDK 88   // padded k-stride (ushorts) = 176 B: 16B-aligned, 2-way banks

__global__ __launch_bounds__(256) void proj_mfma(
    const float* __restrict__ query, const float* __restrict__ memory,
    const float* __restrict__ Wq, const float* __restrict__ Wm,
    const float* __restrict__ bq,
    float* __restrict__ qp, float* __restrict__ kp)
{
    __shared__ ushort As[PBM][PLDK];
    __shared__ ushort Bs[PBN][PLDK];   // stores W^T tile: Bs[n][k]

    const int mtile = blockIdx.x % 160;
    const int ntile = blockIdx.x / 160;
    const int n0 = ntile * PBN;
    const bool is_q = (mtile < 32);
    const float* X = is_q ? (query  + (size_t)mtile * PBM * D_)
                          : (memory + (size_t)(mtile - 32) * PBM * D_);
    const float* W = is_q ? Wq : Wm;
    float* out     = is_q ? (qp + (size_t)mtile * PBM * H_)
                          : (kp + (size_t)(mtile - 32) * PBM * H_);

    const int t = threadIdx.x;
    const int lane = t & 63, w = t >> 6;
    const int wm = (w & 1) * 16, wn = (w >> 1) * 16;

    const int ar  = t >> 4;
    const int akq = t & 15;
    const int bn  = t >> 3;
    const int bk2 = t & 7;

    const int frow = lane & 15;
    const int fkof = (lane >> 4) * 8;

    f32x4 acc = {0.f, 0.f, 0.f, 0.f};

    for (int k0 = 0; k0 < D_; k0 += PBK) {
#pragma unroll
        for (int p = 0; p < 2; ++p) {
            const int row = ar + p * 16;
            const float4 x4 = *(const float4*)(X + (size_t)row * D_ + k0 + akq * 4);
            ushort4 u4;
            u4.x = f2bf(x4.x); u4.y = f2bf(x4.y); u4.z = f2bf(x4.z); u4.w = f2bf(x4.w);
            *(ushort4*)&As[row][akq * 4] = u4;
        }
#pragma unroll
        for (int kp4 = 0; kp4 < 4; ++kp4) {
            const int kk = kp4 * 16 + bk2 * 2;
            const float* wp = W + (size_t)(k0 + kk) * H_ + n0 + bn;
            const float w0 = wp[0], w1 = wp[H_];
            ushort2 u2; u2.x = f2bf(w0); u2.y = f2bf(w1);
            *(ushort2*)&Bs[bn][kk] = u2;
        }
        __syncthreads();
#pragma unroll
        for (int ks = 0; ks < PBK; ks += 32) {
            bf16x8 a = *(const bf16x8*)&As[wm + frow][ks + fkof];
            bf16x8 b = *(const bf16x8*)&Bs[wn + frow][ks + fkof];
            acc = __builtin_amdgcn_mfma_f32_16x16x32_bf16(a, b, acc, 0, 0, 0);
        }
        __syncthreads();
    }

    const int col  = n0 + wn + (lane & 15);
    const int rloc = wm + (lane >> 4) * 4;
    const float bias = is_q ? bq[col] : 0.0f;
#pragma unroll
    for (int r = 0; r < 4; ++r)
        out[(size_t)(rloc + r) * H_ + col] = (acc[r] + bias) * PRESCALE;
}

// ---------------- fused score/softmax/PV ----------------
// One block = (b, 4 q). 512 threads = 8 waves; 256 blocks (1/CU).
// Each wave computes ALL 4 q per kp-row load (4x kp traffic reduction).
__global__ __launch_bounds__(512) void attn_kernel(
    const float* __restrict__ qp,      // [1024][256] prescaled
    const float* __restrict__ kp,      // [4096][256] prescaled
    const float* __restrict__ memory,  // [8][512][512]
    const int*   __restrict__ mask,    // [8][512]
    const float* __restrict__ v,       // [256]
    float* __restrict__ out_wm,        // [1024][512]
    float* __restrict__ out_w)         // [1024][512]
{
    __shared__ float scores[4][512];
    __shared__ int   mlist[512];
    __shared__ int   nact_sh;
    const int t = threadIdx.x;
    const int b  = blockIdx.x & 7;     // all blocks of batch b -> XCD b
    const int qg = blockIdx.x >> 3;    // 0..31
    const int rowbase = b * LQ_ + qg * 4;
    const int w = t >> 6, lane = t & 63;

    for (int i = t; i < 4 * 512; i += 512) (&scores[0][0])[i] = MASKVAL;

    if (w == 0) {
        unsigned base = 0;
        for (int it = 0; it < 8; ++it) {
            int m = it * 64 + lane;
            int act = (mask[b * 512 + m] == 0);
            unsigned long long bal = __ballot(act);
            if (act) {
                int pos = __popcll(bal & ((1ull << lane) - 1ull));
                mlist[base + pos] = m;
            }
            base += __popcll(bal);
        }
        if (lane == 0) nact_sh = (int)base;
    }
    __syncthreads();
    const int nact = nact_sh;

    // ---- phase 1: scores[q][m] = vsum - 2 * sum_h v[h]/(e^{2(qp+kp)}+1) ----
    {
        const int lane16 = lane & 15, mg = lane >> 4;
        float qreg[4][16], vreg[16];
        const float4* vrp = (const float4*)(v + lane16 * 16);
        float sv = 0.0f;
#pragma unroll
        for (int j = 0; j < 4; ++j) {
            float4 c = vrp[j];
            vreg[4 * j + 0] = c.x; vreg[4 * j + 1] = c.y;
            vreg[4 * j + 2] = c.z; vreg[4 * j + 3] = c.w;
            sv += c.x + c.y + c.z + c.w;
        }
        sv += __shfl_xor(sv, 1); sv += __shfl_xor(sv, 2);
        sv += __shfl_xor(sv, 4); sv += __shfl_xor(sv, 8);
#pragma unroll
        for (int q = 0; q < 4; ++q) {
            const float4* qrp = (const float4*)(qp + (size_t)(rowbase + q) * 256 + lane16 * 16);
#pragma unroll
            for (int j = 0; j < 4; ++j) {
                float4 a = qrp[j];
                qreg[q][4 * j + 0] = a.x; qreg[q][4 * j + 1] = a.y;
                qreg[q][4 * j + 2] = a.z; qreg[q][4 * j + 3] = a.w;
            }
        }

        const int nit = (nact + 31) >> 5;
        for (int it = 0; it < nit; ++it) {
            int i = it * 32 + w * 4 + mg;
            if (i < nact) {
                int m = mlist[i];
                const float4* kr = (const float4*)(kp + (size_t)(b * 512 + m) * 256 + lane16 * 16);
                float acc[4] = {0.f, 0.f, 0.f, 0.f};
#pragma unroll
                for (int j = 0; j < 4; ++j) {
                    float4 k4 = kr[j];
                    float kc[4] = {k4.x, k4.y, k4.z, k4.w};
#pragma unroll
                    for (int c = 0; c < 4; ++c) {
                        const int h = 4 * j + c;
                        const float vv = vreg[h];
                        const float kk = kc[c];
#pragma unroll
                        for (int q = 0; q < 4; ++q) {
                            acc[q] = fmaf(vv,
                                __builtin_amdgcn_rcpf(__builtin_amdgcn_exp2f(qreg[q][h] + kk) + 1.0f),
                                acc[q]);
                        }
                    }
                }
#pragma unroll
                for (int q = 0; q < 4; ++q) {
                    float p = acc[q];
                    p += __shfl_xor(p, 1); p += __shfl_xor(p, 2);
                    p += __shfl_xor(p, 4); p += __shfl_xor(p, 8);
                    if (lane16 == 0) scores[q][m] = sv - 2.0f * p;
                }
            }
        }
    }
    __syncthreads();

    // ---- phase 2: softmax per q (waves 0..3) ----
    if (w < 4) {
        const int q = w, row = rowbase + q;
        float s[8], e[8];
        float mx = -INFINITY;
#pragma unroll
        for (int k = 0; k < 8; ++k) { s[k] = scores[q][lane + 64 * k]; mx = fmaxf(mx, s[k]); }
#pragma unroll
        for (int off = 32; off >= 1; off >>= 1) mx = fmaxf(mx, __shfl_xor(mx, off));
        float sum = 0.0f;
#pragma unroll
        for (int k = 0; k < 8; ++k) {
            e[k] = __builtin_amdgcn_exp2f((s[k] - mx) * 1.44269504088896341f);
            sum += e[k];
        }
#pragma unroll
        for (int off = 32; off >= 1; off >>= 1) sum += __shfl_xor(sum, off);
        float rs = __builtin_amdgcn_rcpf(sum);
#pragma unroll
        for (int k = 0; k < 8; ++k) {
            float wt = e[k] * rs;
            scores[q][lane + 64 * k] = wt;
            out_w[(size_t)row * 512 + lane + 64 * k] = wt;
        }
    }
    __syncthreads();

    // ---- phase 3: weighted_memory[q][d] = sum_m w[q][m] * memory[b][m][d] ----
    {
        const int d = t;
        float a0 = 0.f, a1 = 0.f, a2 = 0.f, a3 = 0.f;
        int i = 0;
        for (; i + 2 <= nact; i += 2) {
            int m0 = mlist[i], m1 = mlist[i + 1];
            float v0 = memory[(size_t)(b * 512 + m0) * 512 + d];
            float v1 = memory[(size_t)(b * 512 + m1) * 512 + d];
            a0 = fmaf(scores[0][m1], v1, fmaf(scores[0][m0], v0, a0));
            a1 = fmaf(scores[1][m1], v1, fmaf(scores[1][m0], v0, a1));
            a2 = fmaf(scores[2][m1], v1, fmaf(scores[2][m0], v0, a2));
            a3 = fmaf(scores[3][m1], v1, fmaf(scores[3][m0], v0, a3));
        }
        if (i < nact) {
            int m0 = mlist[i];
            float v0 = memory[(size_t)(b * 512 + m0) * 512 + d];
            a0 = fmaf(scores[0][m0], v0, a0);
            a1 = fmaf(scores[1][m0], v0, a1);
            a2 = fmaf(scores[2][m0], v0, a2);
            a3 = fmaf(scores[3][m0], v0, a3);
        }
        out_wm[(size_t)(rowbase + 0) * 512 + d] = a0;
        out_wm[(size_t)(rowbase + 1) * 512 + d] = a1;
        out_wm[(size_t)(rowbase + 2) * 512 + d] = a2;
        out_wm[(size_t)(rowbase + 3) * 512 + d] = a3;
    }
}

extern "C" void kernel_launch(void* const* d_in, const int* in_sizes, int n_in,
                              void* d_out, int out_size, void* d_ws, size_t ws_size,
                              hipStream_t stream) {
    const float* query  = (const float*)d_in[0];
    const float* memory = (const float*)d_in[1];
    const int*   mask   = (const int*)  d_in[2];
    const float* Wq     = (const float*)d_in[3];
    const float* bq     = (const float*)d_in[4];
    const float* Wm     = (const float*)d_in[5];
    const float* v      = (const float*)d_in[6];

    float* out_wm = (float*)d_out;                         // [1024][512]
    float* out_w  = out_wm + (size_t)B_ * LQ_ * D_;        // [1024][512]

    float* qp = (float*)d_ws;                              // [1024][256]
    float* kp = qp + (size_t)B_ * LQ_ * H_;                // [4096][256]

    hipLaunchKernelGGL(proj_mfma, dim3(160 * (H_ / PBN)), dim3(256), 0, stream,
                       query, memory, Wq, Wm, bq, qp, kp);
    hipLaunchKernelGGL(attn_kernel, dim3(B_ * (LQ_ / 4)), dim3(512), 0, stream,
                       qp, kp, memory, mask, v, out_wm, out_w);
}

// Round 5
// 56.055 us; speedup vs baseline: 3.0169x; 1.1852x over previous
//
#include <hip/hip_runtime.h>
#include <hip/hip_bf16.h>

#define B_   8
#define LQ_  128
#define LM_  512
#define D_   512
#define H_   256
#define MASKVAL -1e24f
#define PRESCALE 2.88539008177792681f  // 2*log2(e): exp2(PRESCALE*x) = e^(2x)

typedef __attribute__((ext_vector_type(8))) short bf16x8;
typedef __attribute__((ext_vector_type(4))) float f32x4;

__device__ __forceinline__ ushort f2bf(float x) {
    return __builtin_bit_cast(ushort, __float2bfloat16(x));
}

// ---------------- MFMA projection GEMM (bf16 inputs, f32 accum) ----------------
#define PBM 32
#define PBN 32
#define PBK 64
#define PLDK 88   // padded k-stride (ushorts) = 176 B: 16B-aligned, 2-way banks

__global__ __launch_bounds__(256) void proj_mfma(
    const float* __restrict__ query, const float* __restrict__ memory,
    const float* __restrict__ Wq, const float* __restrict__ Wm,
    const float* __restrict__ bq,
    float* __restrict__ qp, float* __restrict__ kp)
{
    __shared__ ushort As[PBM][PLDK];
    __shared__ ushort Bs[PBN][PLDK];   // stores W^T tile: Bs[n][k]

    const int mtile = blockIdx.x % 160;
    const int ntile = blockIdx.x / 160;
    const int n0 = ntile * PBN;
    const bool is_q = (mtile < 32);
    const float* X = is_q ? (query  + (size_t)mtile * PBM * D_)
                          : (memory + (size_t)(mtile - 32) * PBM * D_);
    const float* W = is_q ? Wq : Wm;
    float* out     = is_q ? (qp + (size_t)mtile * PBM * H_)
                          : (kp + (size_t)(mtile - 32) * PBM * H_);

    const int t = threadIdx.x;
    const int lane = t & 63, w = t >> 6;
    const int wm = (w & 1) * 16, wn = (w >> 1) * 16;

    const int ar  = t >> 4;   // A staging row
    const int akq = t & 15;   // A k-quad

    const int frow = lane & 15;
    const int fkof = (lane >> 4) * 8;

    f32x4 acc = {0.f, 0.f, 0.f, 0.f};

    for (int k0 = 0; k0 < D_; k0 += PBK) {
        // stage A: X[32][64] f32 -> bf16 (coalesced float4)
#pragma unroll
        for (int p = 0; p < 2; ++p) {
            const int row = ar + p * 16;
            const float4 x4 = *(const float4*)(X + (size_t)row * D_ + k0 + akq * 4);
            ushort4 u4;
            u4.x = f2bf(x4.x); u4.y = f2bf(x4.y); u4.z = f2bf(x4.z); u4.w = f2bf(x4.w);
            *(ushort4*)&As[row][akq * 4] = u4;
        }
        // stage B: W[k0..][n0..n0+31] -> Bs[n][k] transposed; coalesced float4 row loads
#pragma unroll
        for (int p = 0; p < 2; ++p) {
            const int L  = t + p * 256;   // 0..511
            const int kk = L >> 3;        // k-row 0..63
            const int f4 = L & 7;         // float4 slot: 8*4 = 32 n
            const float4 w4 = *(const float4*)(W + (size_t)(k0 + kk) * H_ + n0 + f4 * 4);
            Bs[f4 * 4 + 0][kk] = f2bf(w4.x);
            Bs[f4 * 4 + 1][kk] = f2bf(w4.y);
            Bs[f4 * 4 + 2][kk] = f2bf(w4.z);
            Bs[f4 * 4 + 3][kk] = f2bf(w4.w);
        }
        __syncthreads();
#pragma unroll
        for (int ks = 0; ks < PBK; ks += 32) {
            bf16x8 a = *(const bf16x8*)&As[wm + frow][ks + fkof];
            bf16x8 b = *(const bf16x8*)&Bs[wn + frow][ks + fkof];
            acc = __builtin_amdgcn_mfma_f32_16x16x32_bf16(a, b, acc, 0, 0, 0);
        }
        __syncthreads();
    }

    const int col  = n0 + wn + (lane & 15);
    const int rloc = wm + (lane >> 4) * 4;
    const float bias = is_q ? bq[col] : 0.0f;
#pragma unroll
    for (int r = 0; r < 4; ++r)
        out[(size_t)(rloc + r) * H_ + col] = (acc[r] + bias) * PRESCALE;
}

// ---------------- fused score/softmax/PV ----------------
// One block = (b, 4 q). 512 threads = 8 waves; 256 blocks = 1/CU (fully resident).
// __launch_bounds__(512, 2): we KNOW only 2 waves/SIMD can be resident ->
// give the register allocator the full ~256-VGPR budget so qreg stays in regs.
__global__ __launch_bounds__(512, 2) void attn_kernel(
    const float* __restrict__ qp,      // [1024][256] prescaled
    const float* __restrict__ kp,      // [4096][256] prescaled
    const float* __restrict__ memory,  // [8][512][512]
    const int*   __restrict__ mask,    // [8][512]
    const float* __restrict__ v,       // [256]
    float* __restrict__ out_wm,        // [1024][512]
    float* __restrict__ out_w)         // [1024][512]
{
    __shared__ float scores[4][512];
    __shared__ int   mlist[512];
    __shared__ int   nact_sh;
    const int t = threadIdx.x;
    const int b  = blockIdx.x & 7;     // all blocks of batch b -> XCD b
    const int qg = blockIdx.x >> 3;    // 0..31
    const int rowbase = b * LQ_ + qg * 4;
    const int w = t >> 6, lane = t & 63;

    for (int i = t; i < 4 * 512; i += 512) (&scores[0][0])[i] = MASKVAL;

    if (w == 0) {
        unsigned base = 0;
        for (int it = 0; it < 8; ++it) {
            int m = it * 64 + lane;
            int act = (mask[b * 512 + m] == 0);
            unsigned long long bal = __ballot(act);
            if (act) {
                int pos = __popcll(bal & ((1ull << lane) - 1ull));
                mlist[base + pos] = m;
            }
            base += __popcll(bal);
        }
        if (lane == 0) nact_sh = (int)base;
    }
    __syncthreads();
    const int nact = nact_sh;

    // ---- phase 1: scores[q][m] = vsum - 2 * sum_h v[h]/(e^{2(qp+kp)}+1) ----
    {
        const int lane16 = lane & 15, mg = lane >> 4;
        float qreg[4][16], vreg[16];
        const float4* vrp = (const float4*)(v + lane16 * 16);
        float sv = 0.0f;
#pragma unroll
        for (int j = 0; j < 4; ++j) {
            float4 c = vrp[j];
            vreg[4 * j + 0] = c.x; vreg[4 * j + 1] = c.y;
            vreg[4 * j + 2] = c.z; vreg[4 * j + 3] = c.w;
            sv += c.x + c.y + c.z + c.w;
        }
        sv += __shfl_xor(sv, 1); sv += __shfl_xor(sv, 2);
        sv += __shfl_xor(sv, 4); sv += __shfl_xor(sv, 8);
#pragma unroll
        for (int q = 0; q < 4; ++q) {
            const float4* qrp = (const float4*)(qp + (size_t)(rowbase + q) * 256 + lane16 * 16);
#pragma unroll
            for (int j = 0; j < 4; ++j) {
                float4 a = qrp[j];
                qreg[q][4 * j + 0] = a.x; qreg[q][4 * j + 1] = a.y;
                qreg[q][4 * j + 2] = a.z; qreg[q][4 * j + 3] = a.w;
            }
        }

        const int nit = (nact + 31) >> 5;
        for (int it = 0; it < nit; ++it) {
            int i = it * 32 + w * 4 + mg;
            if (i < nact) {
                int m = mlist[i];
                const float4* kr = (const float4*)(kp + (size_t)(b * 512 + m) * 256 + lane16 * 16);
                float acc[4] = {0.f, 0.f, 0.f, 0.f};
#pragma unroll
                for (int j = 0; j < 4; ++j) {
                    float4 k4 = kr[j];
                    float kc[4] = {k4.x, k4.y, k4.z, k4.w};
#pragma unroll
                    for (int c = 0; c < 4; ++c) {
                        const int h = 4 * j + c;
                        const float vv = vreg[h];
                        const float kk = kc[c];
#pragma unroll
                        for (int q = 0; q < 4; ++q) {
                            acc[q] = fmaf(vv,
                                __builtin_amdgcn_rcpf(__builtin_amdgcn_exp2f(qreg[q][h] + kk) + 1.0f),
                                acc[q]);
                        }
                    }
                }
#pragma unroll
                for (int q = 0; q < 4; ++q) {
                    float p = acc[q];
                    p += __shfl_xor(p, 1); p += __shfl_xor(p, 2);
                    p += __shfl_xor(p, 4); p += __shfl_xor(p, 8);
                    if (lane16 == 0) scores[q][m] = sv - 2.0f * p;
                }
            }
        }
    }
    __syncthreads();

    // ---- phase 2: softmax per q (waves 0..3) ----
    if (w < 4) {
        const int q = w, row = rowbase + q;
        float s[8], e[8];
        float mx = -INFINITY;
#pragma unroll
        for (int k = 0; k < 8; ++k) { s[k] = scores[q][lane + 64 * k]; mx = fmaxf(mx, s[k]); }
#pragma unroll
        for (int off = 32; off >= 1; off >>= 1) mx = fmaxf(mx, __shfl_xor(mx, off));
        float sum = 0.0f;
#pragma unroll
        for (int k = 0; k < 8; ++k) {
            e[k] = __builtin_amdgcn_exp2f((s[k] - mx) * 1.44269504088896341f);
            sum += e[k];
        }
#pragma unroll
        for (int off = 32; off >= 1; off >>= 1) sum += __shfl_xor(sum, off);
        float rs = __builtin_amdgcn_rcpf(sum);
#pragma unroll
        for (int k = 0; k < 8; ++k) {
            float wt = e[k] * rs;
            scores[q][lane + 64 * k] = wt;
            out_w[(size_t)row * 512 + lane + 64 * k] = wt;
        }
    }
    __syncthreads();

    // ---- phase 3: weighted_memory[q][d] = sum_m w[q][m] * memory[b][m][d] ----
    // 4-way m-unroll: 4 independent L2 loads in flight per thread.
    {
        const int d = t;
        const float* mb = memory + (size_t)b * 512 * 512 + d;
        float a0 = 0.f, a1 = 0.f, a2 = 0.f, a3 = 0.f;
        int i = 0;
        for (; i + 4 <= nact; i += 4) {
            int m0 = mlist[i], m1 = mlist[i + 1], m2 = mlist[i + 2], m3 = mlist[i + 3];
            float v0 = mb[(size_t)m0 * 512];
            float v1 = mb[(size_t)m1 * 512];
            float v2 = mb[(size_t)m2 * 512];
            float v3 = mb[(size_t)m3 * 512];
            a0 = fmaf(scores[0][m3], v3, fmaf(scores[0][m2], v2, fmaf(scores[0][m1], v1, fmaf(scores[0][m0], v0, a0))));
            a1 = fmaf(scores[1][m3], v3, fmaf(scores[1][m2], v2, fmaf(scores[1][m1], v1, fmaf(scores[1][m0], v0, a1))));
            a2 = fmaf(scores[2][m3], v3, fmaf(scores[2][m2], v2, fmaf(scores[2][m1], v1, fmaf(scores[2][m0], v0, a2))));
            a3 = fmaf(scores[3][m3], v3, fmaf(scores[3][m2], v2, fmaf(scores[3][m1], v1, fmaf(scores[3][m0], v0, a3))));
        }
        for (; i < nact; ++i) {
            int m0 = mlist[i];
            float v0 = mb[(size_t)m0 * 512];
            a0 = fmaf(scores[0][m0], v0, a0);
            a1 = fmaf(scores[1][m0], v0, a1);
            a2 = fmaf(scores[2][m0], v0, a2);
            a3 = fmaf(scores[3][m0], v0, a3);
        }
        out_wm[(size_t)(rowbase + 0) * 512 + d] = a0;
        out_wm[(size_t)(rowbase + 1) * 512 + d] = a1;
        out_wm[(size_t)(rowbase + 2) * 512 + d] = a2;
        out_wm[(size_t)(rowbase + 3) * 512 + d] = a3;
    }
}

extern "C" void kernel_launch(void* const* d_in, const int* in_sizes, int n_in,
                              void* d_out, int out_size, void* d_ws, size_t ws_size,
                              hipStream_t stream) {
    const float* query  = (const float*)d_in[0];
    const float* memory = (const float*)d_in[1];
    const int*   mask   = (const int*)  d_in[2];
    const float* Wq     = (const float*)d_in[3];
    const float* bq     = (const float*)d_in[4];
    const float* Wm     = (const float*)d_in[5];
    const float* v      = (const float*)d_in[6];

    float* out_wm = (float*)d_out;                         // [1024][512]
    float* out_w  = out_wm + (size_t)B_ * LQ_ * D_;        // [1024][512]

    float* qp = (float*)d_ws;                              // [1024][256]
    float* kp = qp + (size_t)B_ * LQ_ * H_;                // [4096][256]

    hipLaunchKernelGGL(proj_mfma, dim3(160 * (H_ / PBN)), dim3(256), 0, stream,
                       query, memory, Wq, Wm, bq, qp, kp);
    hipLaunchKernelGGL(attn_kernel, dim3(B_ * (LQ_ / 4)), dim3(512), 0, stream,
                       qp, kp, memory, mask, v, out_wm, out_w);
}

// Round 6
// 56.024 us; speedup vs baseline: 3.0186x; 1.0006x over previous
//
#include <hip/hip_runtime.h>
#include <hip/hip_bf16.h>

#define B_   8
#define LQ_  128
#define LM_  512
#define D_   512
#define H_   256
#define MASKVAL -1e24f
#define PRESCALE 2.88539008177792681f  // 2*log2(e): exp2(PRESCALE*x) = e^(2x)

typedef __attribute__((ext_vector_type(8))) short bf16x8;
typedef __attribute__((ext_vector_type(4))) float f32x4;

__device__ __forceinline__ ushort f2bf(float x) {
    return __builtin_bit_cast(ushort, __float2bfloat16(x));
}

// ---------------- MFMA projection GEMM (bf16 inputs, f32 accum) ----------------
#define PBM 32
#define PBN 32
#define PBK 64
#define PLDK 88   // padded k-stride (ushorts) = 176 B: 16B-aligned, 2-way banks

__global__ __launch_bounds__(256) void proj_mfma(
    const float* __restrict__ query, const float* __restrict__ memory,
    const float* __restrict__ Wq, const float* __restrict__ Wm,
    const float* __restrict__ bq,
    float* __restrict__ qp, float* __restrict__ kp)
{
    __shared__ ushort As[PBM][PLDK];
    __shared__ ushort Bs[PBN][PLDK];   // stores W^T tile: Bs[n][k]

    const int mtile = blockIdx.x % 160;
    const int ntile = blockIdx.x / 160;
    const int n0 = ntile * PBN;
    const bool is_q = (mtile < 32);
    const float* X = is_q ? (query  + (size_t)mtile * PBM * D_)
                          : (memory + (size_t)(mtile - 32) * PBM * D_);
    const float* W = is_q ? Wq : Wm;
    float* out     = is_q ? (qp + (size_t)mtile * PBM * H_)
                          : (kp + (size_t)(mtile - 32) * PBM * H_);

    const int t = threadIdx.x;
    const int lane = t & 63, w = t >> 6;
    const int wm = (w & 1) * 16, wn = (w >> 1) * 16;

    const int ar  = t >> 4;   // A staging row
    const int akq = t & 15;   // A k-quad

    const int frow = lane & 15;
    const int fkof = (lane >> 4) * 8;

    f32x4 acc = {0.f, 0.f, 0.f, 0.f};

    for (int k0 = 0; k0 < D_; k0 += PBK) {
#pragma unroll
        for (int p = 0; p < 2; ++p) {
            const int row = ar + p * 16;
            const float4 x4 = *(const float4*)(X + (size_t)row * D_ + k0 + akq * 4);
            ushort4 u4;
            u4.x = f2bf(x4.x); u4.y = f2bf(x4.y); u4.z = f2bf(x4.z); u4.w = f2bf(x4.w);
            *(ushort4*)&As[row][akq * 4] = u4;
        }
#pragma unroll
        for (int p = 0; p < 2; ++p) {
            const int L  = t + p * 256;   // 0..511
            const int kk = L >> 3;        // k-row 0..63
            const int f4 = L & 7;         // float4 slot
            const float4 w4 = *(const float4*)(W + (size_t)(k0 + kk) * H_ + n0 + f4 * 4);
            Bs[f4 * 4 + 0][kk] = f2bf(w4.x);
            Bs[f4 * 4 + 1][kk] = f2bf(w4.y);
            Bs[f4 * 4 + 2][kk] = f2bf(w4.z);
            Bs[f4 * 4 + 3][kk] = f2bf(w4.w);
        }
        __syncthreads();
#pragma unroll
        for (int ks = 0; ks < PBK; ks += 32) {
            bf16x8 a = *(const bf16x8*)&As[wm + frow][ks + fkof];
            bf16x8 b = *(const bf16x8*)&Bs[wn + frow][ks + fkof];
            acc = __builtin_amdgcn_mfma_f32_16x16x32_bf16(a, b, acc, 0, 0, 0);
        }
        __syncthreads();
    }

    const int col  = n0 + wn + (lane & 15);
    const int rloc = wm + (lane >> 4) * 4;
    const float bias = is_q ? bq[col] : 0.0f;
#pragma unroll
    for (int r = 0; r < 4; ++r)
        out[(size_t)(rloc + r) * H_ + col] = (acc[r] + bias) * PRESCALE;
}

// ---------------- fused score/softmax/PV ----------------
// One block = (b, 4 q). 1024 threads = 16 waves = 4 waves/SIMD, 256 blocks (1/CU).
// q and v live in LDS (conflict-free [j][lane16][4] layout) so the compiler
// cannot sink their loads into the m-loop as global re-reads (the R4/R5 stall).
#define RSIG(X) __builtin_amdgcn_rcpf(__builtin_amdgcn_exp2f(X) + 1.0f)

__global__ __launch_bounds__(1024, 4) void attn_kernel(
    const float* __restrict__ qp,      // [1024][256] prescaled
    const float* __restrict__ kp,      // [4096][256] prescaled
    const float* __restrict__ memory,  // [8][512][512]
    const int*   __restrict__ mask,    // [8][512]
    const float* __restrict__ v,       // [256]
    float* __restrict__ out_wm,        // [1024][512]
    float* __restrict__ out_w)         // [1024][512]
{
    __shared__ float scores[4][512];   // 8 KB
    __shared__ float qsw[4][256];      // 4 KB, [q][j*64 + l16*4 + c] = qp[rb+q][l16*16+j*4+c]
    __shared__ float vs[256];          // 1 KB, same layout
    __shared__ int   mlist[512];       // 2 KB
    __shared__ int   nact_sh;
    __shared__ float sv_sh;

    const int t = threadIdx.x;
    const int b  = blockIdx.x & 7;     // all blocks of batch b -> XCD b
    const int qg = blockIdx.x >> 3;    // 0..31
    const int rowbase = b * LQ_ + qg * 4;
    const int w = t >> 6, lane = t & 63;

    // init scores (2 floats/thread)
    ((float2*)&scores[0][0])[t] = make_float2(MASKVAL, MASKVAL);

    if (t < 256) {                      // stage q -> LDS (interleaved layout)
        const int q = t >> 6, j = (t >> 4) & 3, l16 = t & 15;
        const float4 a = *(const float4*)(qp + (size_t)(rowbase + q) * 256 + l16 * 16 + j * 4);
        *(float4*)&qsw[q][j * 64 + l16 * 4] = a;
    } else if (t < 320) {               // wave 4: stage v + compute sv
        const int l = t - 256, j = l >> 4, l16 = l & 15;
        const float4 c = *(const float4*)(v + l16 * 16 + j * 4);
        *(float4*)&vs[j * 64 + l16 * 4] = c;
        float s = c.x + c.y + c.z + c.w;
        s += __shfl_xor(s, 1);  s += __shfl_xor(s, 2);
        s += __shfl_xor(s, 4);  s += __shfl_xor(s, 8);
        s += __shfl_xor(s, 16); s += __shfl_xor(s, 32);
        if (l == 0) sv_sh = s;
    }
    if (w == 15) {                      // wave 15: compact active-m list
        unsigned base = 0;
        for (int it = 0; it < 8; ++it) {
            int m = it * 64 + lane;
            int act = (mask[b * 512 + m] == 0);
            unsigned long long bal = __ballot(act);
            if (act) {
                int pos = __popcll(bal & ((1ull << lane) - 1ull));
                mlist[base + pos] = m;
            }
            base += __popcll(bal);
        }
        if (lane == 0) nact_sh = (int)base;
    }
    __syncthreads();
    const int nact = nact_sh;
    const float sv = sv_sh;

    // ---- phase 1: scores[q][m] = sv - 2 * sum_h v[h] * sigma(qs+ks) ----
    {
        const int lane16 = lane & 15, mg = lane >> 4;
        const int nit = (nact + 63) >> 6;
        for (int it = 0; it < nit; ++it) {
            const int i = it * 64 + w * 4 + mg;
            const bool act = i < nact;
            const int m = act ? mlist[i] : 0;
            const float* kr = kp + (size_t)(b * 512 + m) * 256 + lane16 * 16;
            float acc0 = 0.f, acc1 = 0.f, acc2 = 0.f, acc3 = 0.f;
#pragma unroll
            for (int j = 0; j < 4; ++j) {
                const float4 k4 = *(const float4*)(kr + j * 4);
                const float4 vj = *(const float4*)&vs[j * 64 + lane16 * 4];
                const float4 q0 = *(const float4*)&qsw[0][j * 64 + lane16 * 4];
                const float4 q1 = *(const float4*)&qsw[1][j * 64 + lane16 * 4];
                const float4 q2 = *(const float4*)&qsw[2][j * 64 + lane16 * 4];
                const float4 q3 = *(const float4*)&qsw[3][j * 64 + lane16 * 4];
#define COMP(c) \
                acc0 = fmaf(vj.c, RSIG(q0.c + k4.c), acc0); \
                acc1 = fmaf(vj.c, RSIG(q1.c + k4.c), acc1); \
                acc2 = fmaf(vj.c, RSIG(q2.c + k4.c), acc2); \
                acc3 = fmaf(vj.c, RSIG(q3.c + k4.c), acc3);
                COMP(x) COMP(y) COMP(z) COMP(w)
#undef COMP
            }
            acc0 += __shfl_xor(acc0, 1); acc0 += __shfl_xor(acc0, 2);
            acc0 += __shfl_xor(acc0, 4); acc0 += __shfl_xor(acc0, 8);
            acc1 += __shfl_xor(acc1, 1); acc1 += __shfl_xor(acc1, 2);
            acc1 += __shfl_xor(acc1, 4); acc1 += __shfl_xor(acc1, 8);
            acc2 += __shfl_xor(acc2, 1); acc2 += __shfl_xor(acc2, 2);
            acc2 += __shfl_xor(acc2, 4); acc2 += __shfl_xor(acc2, 8);
            acc3 += __shfl_xor(acc3, 1); acc3 += __shfl_xor(acc3, 2);
            acc3 += __shfl_xor(acc3, 4); acc3 += __shfl_xor(acc3, 8);
            if (lane16 == 0 && act) {
                scores[0][m] = fmaf(-2.f, acc0, sv);
                scores[1][m] = fmaf(-2.f, acc1, sv);
                scores[2][m] = fmaf(-2.f, acc2, sv);
                scores[3][m] = fmaf(-2.f, acc3, sv);
            }
        }
    }
    __syncthreads();

    // ---- phase 2: softmax per q (waves 0..3) ----
    if (w < 4) {
        const int q = w, row = rowbase + q;
        float s[8], e[8];
        float mx = -INFINITY;
#pragma unroll
        for (int k = 0; k < 8; ++k) { s[k] = scores[q][lane + 64 * k]; mx = fmaxf(mx, s[k]); }
#pragma unroll
        for (int off = 32; off >= 1; off >>= 1) mx = fmaxf(mx, __shfl_xor(mx, off));
        float sum = 0.0f;
#pragma unroll
        for (int k = 0; k < 8; ++k) {
            e[k] = __builtin_amdgcn_exp2f((s[k] - mx) * 1.44269504088896341f);
            sum += e[k];
        }
#pragma unroll
        for (int off = 32; off >= 1; off >>= 1) sum += __shfl_xor(sum, off);
        float rs = __builtin_amdgcn_rcpf(sum);
#pragma unroll
        for (int k = 0; k < 8; ++k) {
            float wt = e[k] * rs;
            scores[q][lane + 64 * k] = wt;
            out_w[(size_t)row * 512 + lane + 64 * k] = wt;
        }
    }
    __syncthreads();

    // ---- phase 3: weighted_memory; 2 q per thread, 4-deep MLP ----
    {
        const int d  = t & 511;
        const int qh = t >> 9;             // 0 or 1
        const float* mb = memory + (size_t)b * 512 * 512 + d;
        const float* s0 = scores[qh * 2 + 0];
        const float* s1 = scores[qh * 2 + 1];
        float a0 = 0.f, a1 = 0.f;
        int i = 0;
        for (; i + 4 <= nact; i += 4) {
            const int m0 = mlist[i], m1 = mlist[i + 1], m2 = mlist[i + 2], m3 = mlist[i + 3];
            const float v0 = mb[(size_t)m0 * 512];
            const float v1 = mb[(size_t)m1 * 512];
            const float v2 = mb[(size_t)m2 * 512];
            const float v3 = mb[(size_t)m3 * 512];
            a0 = fmaf(s0[m3], v3, fmaf(s0[m2], v2, fmaf(s0[m1], v1, fmaf(s0[m0], v0, a0))));
            a1 = fmaf(s1[m3], v3, fmaf(s1[m2], v2, fmaf(s1[m1], v1, fmaf(s1[m0], v0, a1))));
        }
        for (; i < nact; ++i) {
            const int m0 = mlist[i];
            const float v0 = mb[(size_t)m0 * 512];
            a0 = fmaf(s0[m0], v0, a0);
            a1 = fmaf(s1[m0], v0, a1);
        }
        out_wm[(size_t)(rowbase + qh * 2 + 0) * 512 + d] = a0;
        out_wm[(size_t)(rowbase + qh * 2 + 1) * 512 + d] = a1;
    }
}

extern "C" void kernel_launch(void* const* d_in, const int* in_sizes, int n_in,
                              void* d_out, int out_size, void* d_ws, size_t ws_size,
                              hipStream_t stream) {
    const float* query  = (const float*)d_in[0];
    const float* memory = (const float*)d_in[1];
    const int*   mask   = (const int*)  d_in[2];
    const float* Wq     = (const float*)d_in[3];
    const float* bq     = (const float*)d_in[4];
    const float* Wm     = (const float*)d_in[5];
    const float* v      = (const float*)d_in[6];

    float* out_wm = (float*)d_out;                         // [1024][512]
    float* out_w  = out_wm + (size_t)B_ * LQ_ * D_;        // [1024][512]

    float* qp = (float*)d_ws;                              // [1024][256]
    float* kp = qp + (size_t)B_ * LQ_ * H_;                // [4096][256]

    hipLaunchKernelGGL(proj_mfma, dim3(160 * (H_ / PBN)), dim3(256), 0, stream,
                       query, memory, Wq, Wm, bq, qp, kp);
    hipLaunchKernelGGL(attn_kernel, dim3(B_ * (LQ_ / 4)), dim3(1024), 0, stream,
                       qp, kp, memory, mask, v, out_wm, out_w);
}

// Round 7
// 51.221 us; speedup vs baseline: 3.3016x; 1.0938x over previous
//
#include <hip/hip_runtime.h>
#include <hip/hip_bf16.h>

#define B_   8
#define LQ_  128
#define LM_  512
#define D_   512
#define H_   256
#define MASKVAL -1e24f
#define PRESCALE 2.88539008177792681f  // 2*log2(e): exp2(PRESCALE*x) = e^(2x)

typedef __attribute__((ext_vector_type(8))) short bf16x8;
typedef __attribute__((ext_vector_type(4))) float f32x4;

__device__ __forceinline__ ushort f2bf(float x) {
    return __builtin_bit_cast(ushort, __float2bfloat16(x));
}

// ---------------- MFMA projection GEMM (bf16 inputs, f32 accum) ----------------
// Epilogue stores E = exp2(PRESCALE * (X@W + bias)) so the attention kernel
// computes sigma(q+k) = rcp(Eq*Ek + 1) with ONE transcendental per element.
#define PBM 32
#define PBN 32
#define PBK 64
#define PLDK 88   // padded k-stride (ushorts) = 176 B: 16B-aligned, 2-way banks

__global__ __launch_bounds__(256) void proj_mfma(
    const float* __restrict__ query, const float* __restrict__ memory,
    const float* __restrict__ Wq, const float* __restrict__ Wm,
    const float* __restrict__ bq,
    float* __restrict__ qp, float* __restrict__ kp)
{
    __shared__ ushort As[PBM][PLDK];
    __shared__ ushort Bs[PBN][PLDK];   // stores W^T tile: Bs[n][k]

    const int mtile = blockIdx.x % 160;
    const int ntile = blockIdx.x / 160;
    const int n0 = ntile * PBN;
    const bool is_q = (mtile < 32);
    const float* X = is_q ? (query  + (size_t)mtile * PBM * D_)
                          : (memory + (size_t)(mtile - 32) * PBM * D_);
    const float* W = is_q ? Wq : Wm;
    float* out     = is_q ? (qp + (size_t)mtile * PBM * H_)
                          : (kp + (size_t)(mtile - 32) * PBM * H_);

    const int t = threadIdx.x;
    const int lane = t & 63, w = t >> 6;
    const int wm = (w & 1) * 16, wn = (w >> 1) * 16;

    const int ar  = t >> 4;   // A staging row
    const int akq = t & 15;   // A k-quad

    const int frow = lane & 15;
    const int fkof = (lane >> 4) * 8;

    f32x4 acc = {0.f, 0.f, 0.f, 0.f};

    for (int k0 = 0; k0 < D_; k0 += PBK) {
#pragma unroll
        for (int p = 0; p < 2; ++p) {
            const int row = ar + p * 16;
            const float4 x4 = *(const float4*)(X + (size_t)row * D_ + k0 + akq * 4);
            ushort4 u4;
            u4.x = f2bf(x4.x); u4.y = f2bf(x4.y); u4.z = f2bf(x4.z); u4.w = f2bf(x4.w);
            *(ushort4*)&As[row][akq * 4] = u4;
        }
#pragma unroll
        for (int p = 0; p < 2; ++p) {
            const int L  = t + p * 256;   // 0..511
            const int kk = L >> 3;        // k-row 0..63
            const int f4 = L & 7;         // float4 slot
            const float4 w4 = *(const float4*)(W + (size_t)(k0 + kk) * H_ + n0 + f4 * 4);
            Bs[f4 * 4 + 0][kk] = f2bf(w4.x);
            Bs[f4 * 4 + 1][kk] = f2bf(w4.y);
            Bs[f4 * 4 + 2][kk] = f2bf(w4.z);
            Bs[f4 * 4 + 3][kk] = f2bf(w4.w);
        }
        __syncthreads();
#pragma unroll
        for (int ks = 0; ks < PBK; ks += 32) {
            bf16x8 a = *(const bf16x8*)&As[wm + frow][ks + fkof];
            bf16x8 b = *(const bf16x8*)&Bs[wn + frow][ks + fkof];
            acc = __builtin_amdgcn_mfma_f32_16x16x32_bf16(a, b, acc, 0, 0, 0);
        }
        __syncthreads();
    }

    const int col  = n0 + wn + (lane & 15);
    const int rloc = wm + (lane >> 4) * 4;
    const float bias = is_q ? bq[col] : 0.0f;
#pragma unroll
    for (int r = 0; r < 4; ++r)
        out[(size_t)(rloc + r) * H_ + col] =
            __builtin_amdgcn_exp2f((acc[r] + bias) * PRESCALE);
}

// ---------------- fused score/softmax/PV ----------------
// One block = (b, 4 q). 1024 threads = 16 waves, 256 blocks (1/CU).
// Inputs qp/kp hold Eq/Ek = exp2-transformed projections (see proj_mfma).
// Lane l16, j-segment, comp c handles h = j*64 + l16*4 + c -> k-loads are
// fully coalesced contiguous 256B quarter-rows per b128 instruction.
__global__ __launch_bounds__(1024, 4) void attn_kernel(
    const float* __restrict__ qp,      // [1024][256] = Eq
    const float* __restrict__ kp,      // [4096][256] = Ek
    const float* __restrict__ memory,  // [8][512][512]
    const int*   __restrict__ mask,    // [8][512]
    const float* __restrict__ v,       // [256]
    float* __restrict__ out_wm,        // [1024][512]
    float* __restrict__ out_w)         // [1024][512]
{
    __shared__ float scores[4][512];   // 8 KB
    __shared__ float qsw[4][256];      // 4 KB (straight copy of Eq rows)
    __shared__ float vs[256];          // 1 KB (raw v)
    __shared__ int   mlist[512];       // 2 KB
    __shared__ int   nact_sh;
    __shared__ float sv_sh;

    const int t = threadIdx.x;
    const int b  = blockIdx.x & 7;     // all blocks of batch b -> XCD b
    const int qg = blockIdx.x >> 3;    // 0..31
    const int rowbase = b * LQ_ + qg * 4;
    const int w = t >> 6, lane = t & 63;

    ((float2*)&scores[0][0])[t] = make_float2(MASKVAL, MASKVAL);

    if (t < 256) {                      // stage Eq -> LDS (straight copy)
        const int q = t >> 6, c4 = t & 63;
        *(float4*)&qsw[q][c4 * 4] = *(const float4*)(qp + (size_t)(rowbase + q) * 256 + c4 * 4);
    } else if (t < 320) {               // wave 4: stage v + compute sv
        const int l = t - 256;
        const float4 c = *(const float4*)(v + l * 4);
        *(float4*)&vs[l * 4] = c;
        float s = c.x + c.y + c.z + c.w;
        s += __shfl_xor(s, 1);  s += __shfl_xor(s, 2);
        s += __shfl_xor(s, 4);  s += __shfl_xor(s, 8);
        s += __shfl_xor(s, 16); s += __shfl_xor(s, 32);
        if (l == 0) sv_sh = s;
    }
    if (w == 15) {                      // wave 15: compact active-m list
        unsigned base = 0;
        for (int it = 0; it < 8; ++it) {
            int m = it * 64 + lane;
            int act = (mask[b * 512 + m] == 0);
            unsigned long long bal = __ballot(act);
            if (act) {
                int pos = __popcll(bal & ((1ull << lane) - 1ull));
                mlist[base + pos] = m;
            }
            base += __popcll(bal);
        }
        if (lane == 0) nact_sh = (int)base;
    }
    __syncthreads();
    const int nact = nact_sh;
    const float sv = sv_sh;

    // ---- phase 1: scores[q][m] = sv - 2 * sum_h v[h] * rcp(Eq*Ek + 1) ----
    {
        const int lane16 = lane & 15;
        const int col = lane16 * 4;
        const int base_i = w * 4 + (lane >> 4);
        const int nit = (nact + 127) >> 7;
        for (int it = 0; it < nit; ++it) {
            const int ia = it * 128 + base_i;
            const int ib = ia + 64;
            const bool acta = ia < nact, actb = ib < nact;
            const int ma = mlist[acta ? ia : 0];
            const int mb = mlist[actb ? ib : 0];
            const float* ka = kp + (size_t)(b * 512 + ma) * 256 + col;
            const float* kb = kp + (size_t)(b * 512 + mb) * 256 + col;
            // 8 independent coalesced b128 loads issued upfront
            const float4 kA0 = *(const float4*)(ka);
            const float4 kA1 = *(const float4*)(ka + 64);
            const float4 kA2 = *(const float4*)(ka + 128);
            const float4 kA3 = *(const float4*)(ka + 192);
            const float4 kB0 = *(const float4*)(kb);
            const float4 kB1 = *(const float4*)(kb + 64);
            const float4 kB2 = *(const float4*)(kb + 128);
            const float4 kB3 = *(const float4*)(kb + 192);
            float a0 = 0.f, a1 = 0.f, a2 = 0.f, a3 = 0.f;
            float b0 = 0.f, b1 = 0.f, b2 = 0.f, b3 = 0.f;
#define COMP(C, KA, KB) \
            a0 = fmaf(vj.C, __builtin_amdgcn_rcpf(fmaf(q0.C, KA.C, 1.0f)), a0); \
            a1 = fmaf(vj.C, __builtin_amdgcn_rcpf(fmaf(q1.C, KA.C, 1.0f)), a1); \
            a2 = fmaf(vj.C, __builtin_amdgcn_rcpf(fmaf(q2.C, KA.C, 1.0f)), a2); \
            a3 = fmaf(vj.C, __builtin_amdgcn_rcpf(fmaf(q3.C, KA.C, 1.0f)), a3); \
            b0 = fmaf(vj.C, __builtin_amdgcn_rcpf(fmaf(q0.C, KB.C, 1.0f)), b0); \
            b1 = fmaf(vj.C, __builtin_amdgcn_rcpf(fmaf(q1.C, KB.C, 1.0f)), b1); \
            b2 = fmaf(vj.C, __builtin_amdgcn_rcpf(fmaf(q2.C, KB.C, 1.0f)), b2); \
            b3 = fmaf(vj.C, __builtin_amdgcn_rcpf(fmaf(q3.C, KB.C, 1.0f)), b3);
#define JBLK(J, KA, KB) { \
            const float4 vj = *(const float4*)&vs[J * 64 + col]; \
            const float4 q0 = *(const float4*)&qsw[0][J * 64 + col]; \
            const float4 q1 = *(const float4*)&qsw[1][J * 64 + col]; \
            const float4 q2 = *(const float4*)&qsw[2][J * 64 + col]; \
            const float4 q3 = *(const float4*)&qsw[3][J * 64 + col]; \
            COMP(x, KA, KB) COMP(y, KA, KB) COMP(z, KA, KB) COMP(w, KA, KB) }
            JBLK(0, kA0, kB0)
            JBLK(1, kA1, kB1)
            JBLK(2, kA2, kB2)
            JBLK(3, kA3, kB3)
#undef JBLK
#undef COMP
#define RED(X) X += __shfl_xor(X, 1); X += __shfl_xor(X, 2); \
               X += __shfl_xor(X, 4); X += __shfl_xor(X, 8);
            RED(a0) RED(a1) RED(a2) RED(a3) RED(b0) RED(b1) RED(b2) RED(b3)
#undef RED
            if (lane16 == 0) {
                if (acta) {
                    scores[0][ma] = fmaf(-2.f, a0, sv);
                    scores[1][ma] = fmaf(-2.f, a1, sv);
                    scores[2][ma] = fmaf(-2.f, a2, sv);
                    scores[3][ma] = fmaf(-2.f, a3, sv);
                }
                if (actb) {
                    scores[0][mb] = fmaf(-2.f, b0, sv);
                    scores[1][mb] = fmaf(-2.f, b1, sv);
                    scores[2][mb] = fmaf(-2.f, b2, sv);
                    scores[3][mb] = fmaf(-2.f, b3, sv);
                }
            }
        }
    }
    __syncthreads();

    // ---- phase 2: softmax per q (waves 0..3) ----
    if (w < 4) {
        const int q = w, row = rowbase + q;
        float s[8], e[8];
        float mx = -INFINITY;
#pragma unroll
        for (int k = 0; k < 8; ++k) { s[k] = scores[q][lane + 64 * k]; mx = fmaxf(mx, s[k]); }
#pragma unroll
        for (int off = 32; off >= 1; off >>= 1) mx = fmaxf(mx, __shfl_xor(mx, off));
        float sum = 0.0f;
#pragma unroll
        for (int k = 0; k < 8; ++k) {
            e[k] = __builtin_amdgcn_exp2f((s[k] - mx) * 1.44269504088896341f);
            sum += e[k];
        }
#pragma unroll
        for (int off = 32; off >= 1; off >>= 1) sum += __shfl_xor(sum, off);
        float rs = __builtin_amdgcn_rcpf(sum);
#pragma unroll
        for (int k = 0; k < 8; ++k) {
            float wt = e[k] * rs;
            scores[q][lane + 64 * k] = wt;
            out_w[(size_t)row * 512 + lane + 64 * k] = wt;
        }
    }
    __syncthreads();

    // ---- phase 3: weighted_memory; 2 q per thread, 4-deep MLP ----
    {
        const int d  = t & 511;
        const int qh = t >> 9;             // 0 or 1
        const float* mb = memory + (size_t)b * 512 * 512 + d;
        const float* s0 = scores[qh * 2 + 0];
        const float* s1 = scores[qh * 2 + 1];
        float a0 = 0.f, a1 = 0.f;
        int i = 0;
        for (; i + 4 <= nact; i += 4) {
            const int m0 = mlist[i], m1 = mlist[i + 1], m2 = mlist[i + 2], m3 = mlist[i + 3];
            const float v0 = mb[(size_t)m0 * 512];
            const float v1 = mb[(size_t)m1 * 512];
            const float v2 = mb[(size_t)m2 * 512];
            const float v3 = mb[(size_t)m3 * 512];
            a0 = fmaf(s0[m3], v3, fmaf(s0[m2], v2, fmaf(s0[m1], v1, fmaf(s0[m0], v0, a0))));
            a1 = fmaf(s1[m3], v3, fmaf(s1[m2], v2, fmaf(s1[m1], v1, fmaf(s1[m0], v0, a1))));
        }
        for (; i < nact; ++i) {
            const int m0 = mlist[i];
            const float v0 = mb[(size_t)m0 * 512];
            a0 = fmaf(s0[m0], v0, a0);
            a1 = fmaf(s1[m0], v0, a1);
        }
        out_wm[(size_t)(rowbase + qh * 2 + 0) * 512 + d] = a0;
        out_wm[(size_t)(rowbase + qh * 2 + 1) * 512 + d] = a1;
    }
}

extern "C" void kernel_launch(void* const* d_in, const int* in_sizes, int n_in,
                              void* d_out, int out_size, void* d_ws, size_t ws_size,
                              hipStream_t stream) {
    const float* query  = (const float*)d_in[0];
    const float* memory = (const float*)d_in[1];
    const int*   mask   = (const int*)  d_in[2];
    const float* Wq     = (const float*)d_in[3];
    const float* bq     = (const float*)d_in[4];
    const float* Wm     = (const float*)d_in[5];
    const float* v      = (const float*)d_in[6];

    float* out_wm = (float*)d_out;                         // [1024][512]
    float* out_w  = out_wm + (size_t)B_ * LQ_ * D_;        // [1024][512]

    float* qp = (float*)d_ws;                              // [1024][256] = Eq
    float* kp = qp + (size_t)B_ * LQ_ * H_;                // [4096][256] = Ek

    hipLaunchKernelGGL(proj_mfma, dim3(160 * (H_ / PBN)), dim3(256), 0, stream,
                       query, memory, Wq, Wm, bq, qp, kp);
    hipLaunchKernelGGL(attn_kernel, dim3(B_ * (LQ_ / 4)), dim3(1024), 0, stream,
                       qp, kp, memory, mask, v, out_wm, out_w);
}

// Round 8
// 45.776 us; speedup vs baseline: 3.6944x; 1.1190x over previous
//
#include <hip/hip_runtime.h>
#include <hip/hip_bf16.h>

#define B_   8
#define LQ_  128
#define LM_  512
#define D_   512
#define H_   256
#define MASKVAL -1e24f
#define PRESCALE 2.88539008177792681f  // 2*log2(e): exp2(PRESCALE*x) = e^(2x)

typedef __attribute__((ext_vector_type(8))) short bf16x8;
typedef __attribute__((ext_vector_type(4))) float f32x4;

__device__ __forceinline__ ushort f2bf(float x) {
    return __builtin_bit_cast(ushort, __float2bfloat16(x));
}

// ---------------- MFMA projection GEMM (bf16 inputs, f32 accum) ----------------
// Epilogue stores E = exp2(PRESCALE * (X@W + bias)) so the attention kernel
// computes sigma(q+k) = rcp(Eq*Ek + 1) with ONE transcendental per element.
#define PBM 32
#define PBN 32
#define PBK 64
#define PLDK 88   // padded k-stride (ushorts) = 176 B: 16B-aligned, 2-way banks

__global__ __launch_bounds__(256) void proj_mfma(
    const float* __restrict__ query, const float* __restrict__ memory,
    const float* __restrict__ Wq, const float* __restrict__ Wm,
    const float* __restrict__ bq,
    float* __restrict__ qp, float* __restrict__ kp)
{
    __shared__ ushort As[PBM][PLDK];
    __shared__ ushort Bs[PBN][PLDK];   // stores W^T tile: Bs[n][k]

    const int mtile = blockIdx.x % 160;
    const int ntile = blockIdx.x / 160;
    const int n0 = ntile * PBN;
    const bool is_q = (mtile < 32);
    const float* X = is_q ? (query  + (size_t)mtile * PBM * D_)
                          : (memory + (size_t)(mtile - 32) * PBM * D_);
    const float* W = is_q ? Wq : Wm;
    float* out     = is_q ? (qp + (size_t)mtile * PBM * H_)
                          : (kp + (size_t)(mtile - 32) * PBM * H_);

    const int t = threadIdx.x;
    const int lane = t & 63, w = t >> 6;
    const int wm = (w & 1) * 16, wn = (w >> 1) * 16;

    const int ar  = t >> 4;   // A staging row
    const int akq = t & 15;   // A k-quad

    const int frow = lane & 15;
    const int fkof = (lane >> 4) * 8;

    f32x4 acc = {0.f, 0.f, 0.f, 0.f};

    for (int k0 = 0; k0 < D_; k0 += PBK) {
#pragma unroll
        for (int p = 0; p < 2; ++p) {
            const int row = ar + p * 16;
            const float4 x4 = *(const float4*)(X + (size_t)row * D_ + k0 + akq * 4);
            ushort4 u4;
            u4.x = f2bf(x4.x); u4.y = f2bf(x4.y); u4.z = f2bf(x4.z); u4.w = f2bf(x4.w);
            *(ushort4*)&As[row][akq * 4] = u4;
        }
#pragma unroll
        for (int p = 0; p < 2; ++p) {
            const int L  = t + p * 256;   // 0..511
            const int kk = L >> 3;        // k-row 0..63
            const int f4 = L & 7;         // float4 slot
            const float4 w4 = *(const float4*)(W + (size_t)(k0 + kk) * H_ + n0 + f4 * 4);
            Bs[f4 * 4 + 0][kk] = f2bf(w4.x);
            Bs[f4 * 4 + 1][kk] = f2bf(w4.y);
            Bs[f4 * 4 + 2][kk] = f2bf(w4.z);
            Bs[f4 * 4 + 3][kk] = f2bf(w4.w);
        }
        __syncthreads();
#pragma unroll
        for (int ks = 0; ks < PBK; ks += 32) {
            bf16x8 a = *(const bf16x8*)&As[wm + frow][ks + fkof];
            bf16x8 b = *(const bf16x8*)&Bs[wn + frow][ks + fkof];
            acc = __builtin_amdgcn_mfma_f32_16x16x32_bf16(a, b, acc, 0, 0, 0);
        }
        __syncthreads();
    }

    const int col  = n0 + wn + (lane & 15);
    const int rloc = wm + (lane >> 4) * 4;
    const float bias = is_q ? bq[col] : 0.0f;
#pragma unroll
    for (int r = 0; r < 4; ++r)
        out[(size_t)(rloc + r) * H_ + col] =
            __builtin_amdgcn_exp2f((acc[r] + bias) * PRESCALE);
}

// ---------------- fused score/softmax/PV ----------------
// One block = (b, 2 q). 512 threads = 8 waves; 512 blocks = 2 blocks/CU so
// one block's VALU-bound phase 1 overlaps the other's VMEM-bound phase 3.
// float4 accumulators -> v_pk_fma_f32 packing for all non-rcp math.
__global__ __launch_bounds__(512, 4) void attn_kernel(
    const float* __restrict__ qp,      // [1024][256] = Eq
    const float* __restrict__ kp,      // [4096][256] = Ek
    const float* __restrict__ memory,  // [8][512][512]
    const int*   __restrict__ mask,    // [8][512]
    const float* __restrict__ v,       // [256]
    float* __restrict__ out_wm,        // [1024][512]
    float* __restrict__ out_w)         // [1024][512]
{
    __shared__ float scores[2][512];   // 4 KB
    __shared__ float qsw[2][256];      // 2 KB
    __shared__ float vs[256];          // 1 KB
    __shared__ int   mlist[512];       // 2 KB
    __shared__ int   nact_sh;
    __shared__ float sv_sh;

    const int t = threadIdx.x;
    const int b  = blockIdx.x & 7;     // all blocks of batch b -> XCD b
    const int qg = blockIdx.x >> 3;    // 0..63
    const int rowbase = b * LQ_ + qg * 2;
    const int w = t >> 6, lane = t & 63;

    ((float2*)&scores[0][0])[t] = make_float2(MASKVAL, MASKVAL);

    if (t < 128) {                      // stage Eq rows (straight copy)
        const int q = t >> 6, c4 = t & 63;
        *(float4*)&qsw[q][c4 * 4] = *(const float4*)(qp + (size_t)(rowbase + q) * 256 + c4 * 4);
    } else if (t < 192) {               // wave 2: stage v + compute sv
        const int l = t - 128;
        const float4 c = *(const float4*)(v + l * 4);
        *(float4*)&vs[l * 4] = c;
        float s = c.x + c.y + c.z + c.w;
        s += __shfl_xor(s, 1);  s += __shfl_xor(s, 2);
        s += __shfl_xor(s, 4);  s += __shfl_xor(s, 8);
        s += __shfl_xor(s, 16); s += __shfl_xor(s, 32);
        if (l == 0) sv_sh = s;
    }
    if (w == 7) {                       // wave 7: compact active-m list
        unsigned base = 0;
        for (int it = 0; it < 8; ++it) {
            int m = it * 64 + lane;
            int act = (mask[b * 512 + m] == 0);
            unsigned long long bal = __ballot(act);
            if (act) {
                int pos = __popcll(bal & ((1ull << lane) - 1ull));
                mlist[base + pos] = m;
            }
            base += __popcll(bal);
        }
        if (lane == 0) nact_sh = (int)base;
    }
    __syncthreads();
    const int nact = nact_sh;
    const float sv = sv_sh;

    // ---- phase 1: scores[q][m] = sv - 2 * sum_h v[h] * rcp(Eq*Ek + 1) ----
    {
        const int lane16 = lane & 15;
        const int col = lane16 * 4;
        const int base_i = w * 4 + (lane >> 4);   // 0..31
        const f32x4 ones = {1.f, 1.f, 1.f, 1.f};
        const int nit = (nact + 63) >> 6;
        for (int it = 0; it < nit; ++it) {
            const int ia = it * 64 + base_i;
            const int ib = ia + 32;
            const bool acta = ia < nact, actb = ib < nact;
            const int ma = mlist[acta ? ia : 0];
            const int mb = mlist[actb ? ib : 0];
            const float* ka = kp + (size_t)(b * 512 + ma) * 256 + col;
            const float* kb = kp + (size_t)(b * 512 + mb) * 256 + col;
            // 8 independent coalesced b128 loads issued upfront
            const f32x4 kA0 = *(const f32x4*)(ka);
            const f32x4 kA1 = *(const f32x4*)(ka + 64);
            const f32x4 kA2 = *(const f32x4*)(ka + 128);
            const f32x4 kA3 = *(const f32x4*)(ka + 192);
            const f32x4 kB0 = *(const f32x4*)(kb);
            const f32x4 kB1 = *(const f32x4*)(kb + 64);
            const f32x4 kB2 = *(const f32x4*)(kb + 128);
            const f32x4 kB3 = *(const f32x4*)(kb + 192);
            f32x4 aA0 = {0,0,0,0}, aA1 = {0,0,0,0};
            f32x4 aB0 = {0,0,0,0}, aB1 = {0,0,0,0};
#define SIG4(Q, K) ({ f32x4 p_ = __builtin_elementwise_fma(Q, K, ones); \
            f32x4 r_; r_.x = __builtin_amdgcn_rcpf(p_.x); r_.y = __builtin_amdgcn_rcpf(p_.y); \
            r_.z = __builtin_amdgcn_rcpf(p_.z); r_.w = __builtin_amdgcn_rcpf(p_.w); r_; })
#define JBLK(J, KA, KB) { \
            const f32x4 vv = *(const f32x4*)&vs[J * 64 + col]; \
            const f32x4 q0 = *(const f32x4*)&qsw[0][J * 64 + col]; \
            const f32x4 q1 = *(const f32x4*)&qsw[1][J * 64 + col]; \
            aA0 = __builtin_elementwise_fma(vv, SIG4(q0, KA), aA0); \
            aA1 = __builtin_elementwise_fma(vv, SIG4(q1, KA), aA1); \
            aB0 = __builtin_elementwise_fma(vv, SIG4(q0, KB), aB0); \
            aB1 = __builtin_elementwise_fma(vv, SIG4(q1, KB), aB1); }
            JBLK(0, kA0, kB0)
            JBLK(1, kA1, kB1)
            JBLK(2, kA2, kB2)
            JBLK(3, kA3, kB3)
#undef JBLK
#undef SIG4
            float a0 = (aA0.x + aA0.y) + (aA0.z + aA0.w);
            float a1 = (aA1.x + aA1.y) + (aA1.z + aA1.w);
            float b0 = (aB0.x + aB0.y) + (aB0.z + aB0.w);
            float b1 = (aB1.x + aB1.y) + (aB1.z + aB1.w);
#define RED(X) X += __shfl_xor(X, 1); X += __shfl_xor(X, 2); \
               X += __shfl_xor(X, 4); X += __shfl_xor(X, 8);
            RED(a0) RED(a1) RED(b0) RED(b1)
#undef RED
            if (lane16 == 0) {
                if (acta) {
                    scores[0][ma] = fmaf(-2.f, a0, sv);
                    scores[1][ma] = fmaf(-2.f, a1, sv);
                }
                if (actb) {
                    scores[0][mb] = fmaf(-2.f, b0, sv);
                    scores[1][mb] = fmaf(-2.f, b1, sv);
                }
            }
        }
    }
    __syncthreads();

    // ---- phase 2: softmax per q (waves 0..1) ----
    if (w < 2) {
        const int q = w, row = rowbase + q;
        float s[8], e[8];
        float mx = -INFINITY;
#pragma unroll
        for (int k = 0; k < 8; ++k) { s[k] = scores[q][lane + 64 * k]; mx = fmaxf(mx, s[k]); }
#pragma unroll
        for (int off = 32; off >= 1; off >>= 1) mx = fmaxf(mx, __shfl_xor(mx, off));
        float sum = 0.0f;
#pragma unroll
        for (int k = 0; k < 8; ++k) {
            e[k] = __builtin_amdgcn_exp2f((s[k] - mx) * 1.44269504088896341f);
            sum += e[k];
        }
#pragma unroll
        for (int off = 32; off >= 1; off >>= 1) sum += __shfl_xor(sum, off);
        float rs = __builtin_amdgcn_rcpf(sum);
#pragma unroll
        for (int k = 0; k < 8; ++k) {
            float wt = e[k] * rs;
            scores[q][lane + 64 * k] = wt;
            out_w[(size_t)row * 512 + lane + 64 * k] = wt;
        }
    }
    __syncthreads();

    // ---- phase 3: weighted_memory; d = t, both q per thread, 4-deep MLP ----
    {
        const int d = t;
        const float* mb = memory + (size_t)b * 512 * 512 + d;
        const float* s0 = scores[0];
        const float* s1 = scores[1];
        float a0 = 0.f, a1 = 0.f;
        int i = 0;
        for (; i + 4 <= nact; i += 4) {
            const int m0 = mlist[i], m1 = mlist[i + 1], m2 = mlist[i + 2], m3 = mlist[i + 3];
            const float v0 = mb[(size_t)m0 * 512];
            const float v1 = mb[(size_t)m1 * 512];
            const float v2 = mb[(size_t)m2 * 512];
            const float v3 = mb[(size_t)m3 * 512];
            a0 = fmaf(s0[m3], v3, fmaf(s0[m2], v2, fmaf(s0[m1], v1, fmaf(s0[m0], v0, a0))));
            a1 = fmaf(s1[m3], v3, fmaf(s1[m2], v2, fmaf(s1[m1], v1, fmaf(s1[m0], v0, a1))));
        }
        for (; i < nact; ++i) {
            const int m0 = mlist[i];
            const float v0 = mb[(size_t)m0 * 512];
            a0 = fmaf(s0[m0], v0, a0);
            a1 = fmaf(s1[m0], v0, a1);
        }
        out_wm[(size_t)(rowbase + 0) * 512 + d] = a0;
        out_wm[(size_t)(rowbase + 1) * 512 + d] = a1;
    }
}

extern "C" void kernel_launch(void* const* d_in, const int* in_sizes, int n_in,
                              void* d_out, int out_size, void* d_ws, size_t ws_size,
                              hipStream_t stream) {
    const float* query  = (const float*)d_in[0];
    const float* memory = (const float*)d_in[1];
    const int*   mask   = (const int*)  d_in[2];
    const float* Wq     = (const float*)d_in[3];
    const float* bq     = (const float*)d_in[4];
    const float* Wm     = (const float*)d_in[5];
    const float* v      = (const float*)d_in[6];

    float* out_wm = (float*)d_out;                         // [1024][512]
    float* out_w  = out_wm + (size_t)B_ * LQ_ * D_;        // [1024][512]

    float* qp = (float*)d_ws;                              // [1024][256] = Eq
    float* kp = qp + (size_t)B_ * LQ_ * H_;                // [4096][256] = Ek

    hipLaunchKernelGGL(proj_mfma, dim3(160 * (H_ / PBN)), dim3(256), 0, stream,
                       query, memory, Wq, Wm, bq, qp, kp);
    hipLaunchKernelGGL(attn_kernel, dim3(B_ * (LQ_ / 2)), dim3(512), 0, stream,
                       qp, kp, memory, mask, v, out_wm, out_w);
}